// Round 1
// baseline (1429.161 us; speedup 1.0000x reference)
//
#include <hip/hip_runtime.h>
#include <hip/hip_bf16.h>
#include <stdint.h>

// CapsNet forward. Sizes: B=512, conv1 1->256 9x9 s1 (28->20), pc 256->256 9x9 s2 (20->6),
// routes R=1152, caps C=10, I=8, O=16, encoder 160->512->9.

typedef __bf16 bf16_t;
typedef __bf16 bf16x4 __attribute__((ext_vector_type(4)));
typedef __bf16 bf16x8 __attribute__((ext_vector_type(8)));
typedef float f32x4 __attribute__((ext_vector_type(4)));

__device__ __forceinline__ void gload_lds16(const void* g, void* l) {
    __builtin_amdgcn_global_load_lds((const __attribute__((address_space(1))) void*)g,
                                     (__attribute__((address_space(3))) void*)l, 16, 0, 0);
}

// ---------------- prep kernels ----------------
__global__ void k_init_bij(float* bij) {
    int i = blockIdx.x * 256 + threadIdx.x;
    if (i < 1152 * 10) bij[i] = 0.f;
}

// enc_w1 [512][160] -> w1t [160][512]
__global__ void k_w1t(const float* __restrict__ w1, float* __restrict__ w1t) {
    int i = blockIdx.x * 256 + threadIdx.x;  // 81920
    int j = i / 160, k = i % 160;
    w1t[k * 512 + j] = w1[i];
}

// pc_w f32 [oc][ic][81] -> W2t bf16 [oc][k] with k = t*256 + ic  (t = kh*9+kw)
__global__ void k_w2t(const float* __restrict__ pcw, bf16_t* __restrict__ w2t) {
    __shared__ bf16_t tmp[20736];
    int oc = blockIdx.x;
    const float* src = pcw + (size_t)oc * 20736;
    for (int q = threadIdx.x; q < 20736; q += 256) {
        int ic = q / 81, t = q % 81;
        tmp[t * 256 + ic] = (bf16_t)src[q];
    }
    __syncthreads();
    bf16_t* dst = w2t + (size_t)oc * 20736;
    for (int q = threadIdx.x; q < 20736; q += 256) dst[q] = tmp[q];
}

// ---------------- conv1 + relu -> x_t NHWC bf16 [b][20][20][256] ----------------
__global__ __launch_bounds__(256) void k_conv1(const float* __restrict__ data,
                                               const float* __restrict__ cw,
                                               const float* __restrict__ cb,
                                               bf16_t* __restrict__ xt) {
    __shared__ float img[784];
    __shared__ float w4[64 * 81];
    int b = blockIdx.x >> 2, ocb = blockIdx.x & 3;
    int tid = threadIdx.x;
    for (int i = tid; i < 784; i += 256) img[i] = data[b * 784 + i];
    for (int i = tid; i < 5184; i += 256) w4[i] = cw[ocb * 5184 + i];
    __syncthreads();
    int q = tid & 15, pg0 = tid >> 4;
    float bias[4];
#pragma unroll
    for (int j = 0; j < 4; ++j) bias[j] = cb[ocb * 64 + q * 4 + j];
    for (int pg = pg0; pg < 100; pg += 16) {
        int oh = pg / 5, ow0 = (pg % 5) * 4;
        float acc[4][4];
#pragma unroll
        for (int l = 0; l < 4; ++l)
#pragma unroll
            for (int j = 0; j < 4; ++j) acc[l][j] = 0.f;
        for (int kh = 0; kh < 9; ++kh) {
#pragma unroll
            for (int kw = 0; kw < 9; ++kw) {
                float wv[4], iv[4];
#pragma unroll
                for (int j = 0; j < 4; ++j) wv[j] = w4[(q * 4 + j) * 81 + kh * 9 + kw];
#pragma unroll
                for (int l = 0; l < 4; ++l) iv[l] = img[(oh + kh) * 28 + ow0 + l + kw];
#pragma unroll
                for (int l = 0; l < 4; ++l)
#pragma unroll
                    for (int j = 0; j < 4; ++j) acc[l][j] += wv[j] * iv[l];
            }
        }
#pragma unroll
        for (int l = 0; l < 4; ++l) {
            int pos = oh * 20 + ow0 + l;
            size_t base = ((size_t)(b * 400 + pos)) * 256 + ocb * 64 + q * 4;
            bf16x4 vv;
#pragma unroll
            for (int j = 0; j < 4; ++j) vv[j] = (bf16_t)fmaxf(acc[l][j] + bias[j], 0.f);
            *(bf16x4*)&xt[base] = vv;
        }
    }
}

// ---------------- PrimaryCaps conv as implicit GEMM, bf16 MFMA ----------------
// C[M=18432][N=256] = A x B ; m=b*36+pos, n=oc, k=(kh*9+kw)*256+ic
// grid 576 = 144 m-tiles x 2 n-tiles x 2 k-splits ; tile 128x128, BK=64
__global__ __launch_bounds__(256) void k_pcgemm(const bf16_t* __restrict__ xt,
                                                const bf16_t* __restrict__ w2t,
                                                float* __restrict__ partA,
                                                float* __restrict__ partB) {
    __shared__ __align__(16) bf16_t As[128 * 64];
    __shared__ __align__(16) bf16_t Bs[128 * 64];
    int bid = blockIdx.x;
    int mt = bid % 144;
    int nt = (bid / 144) & 1;
    int ks = bid / 288;
    int m0 = mt * 128, n0 = nt * 128;
    int tid = threadIdx.x, lane = tid & 63, wave = tid >> 6;

    int arow[4];
#pragma unroll
    for (int p = 0; p < 4; ++p) {
        int m = m0 + p * 32 + (tid >> 3);
        int bb = m / 36, pos = m % 36;
        int oh = pos / 6, ow = pos % 6;
        arow[p] = ((bb * 20 + oh * 2) * 20 + ow * 2) * 256;
    }
    const bf16_t* bbase = w2t + (size_t)(n0 + (tid >> 3)) * 20736 + (tid & 7) * 8;
    bf16_t* aldst = As + tid * 8;
    bf16_t* bldst = Bs + tid * 8;

    f32x4 acc[4][4];
#pragma unroll
    for (int mi = 0; mi < 4; ++mi)
#pragma unroll
        for (int ni = 0; ni < 4; ++ni) acc[mi][ni] = (f32x4){0.f, 0.f, 0.f, 0.f};

    int s0 = ks * 162;
    int t0 = s0 >> 2;
    int icb = s0 & 3;
    int kh = t0 / 9, kw = t0 - (t0 / 9) * 9;

    for (int it = 0; it < 162; ++it) {
        int aoff = (kh * 20 + kw) * 256 + icb * 64 + (tid & 7) * 8;
        const bf16_t* bsrc = bbase + (size_t)(s0 + it) * 64;
#pragma unroll
        for (int p = 0; p < 4; ++p) {
            gload_lds16(xt + arow[p] + aoff, aldst + p * 2048);
            gload_lds16(bsrc + (size_t)p * 32 * 20736, bldst + p * 2048);
        }
        __syncthreads();
        int mr = (wave >> 1) * 64 + (lane & 15);
        int nr = (wave & 1) * 64 + (lane & 15);
        int ko = (lane >> 4) * 8;
#pragma unroll
        for (int kk = 0; kk < 2; ++kk) {
            bf16x8 af[4], bfr[4];
#pragma unroll
            for (int i = 0; i < 4; ++i) af[i] = *(const bf16x8*)&As[(mr + i * 16) * 64 + kk * 32 + ko];
#pragma unroll
            for (int i = 0; i < 4; ++i) bfr[i] = *(const bf16x8*)&Bs[(nr + i * 16) * 64 + kk * 32 + ko];
#pragma unroll
            for (int mi = 0; mi < 4; ++mi)
#pragma unroll
                for (int ni = 0; ni < 4; ++ni)
                    acc[mi][ni] = __builtin_amdgcn_mfma_f32_16x16x32_bf16(af[mi], bfr[ni], acc[mi][ni], 0, 0, 0);
        }
        __syncthreads();
        if (++icb == 4) { icb = 0; if (++kw == 9) { kw = 0; ++kh; } }
    }

    float* out = ks ? partB : partA;
    int mbase = m0 + (wave >> 1) * 64 + (lane >> 4) * 4;
    int nbase = n0 + (wave & 1) * 64 + (lane & 15);
#pragma unroll
    for (int mi = 0; mi < 4; ++mi)
#pragma unroll
        for (int ni = 0; ni < 4; ++ni)
#pragma unroll
            for (int j = 0; j < 4; ++j)
                out[(size_t)(mbase + mi * 16 + j) * 256 + nbase + ni * 16] = acc[mi][ni][j];
}

// ---------------- squash: part[m][n] (x2 k-splits) + bias -> u[b][flat] ----------------
// flat = oc*36 + pos ; route r = flat/8
__global__ void k_squash(const float* __restrict__ pA, const float* __restrict__ pB,
                         const float* __restrict__ pcb, float* __restrict__ u) {
    int idx = blockIdx.x * 256 + threadIdx.x;  // 589824
    int b = idx / 1152, r = idx % 1152;
    int flat0 = r * 8;
    float val[8];
    float sn = 0.f;
#pragma unroll
    for (int e = 0; e < 8; ++e) {
        int flat = flat0 + e;
        int oc = flat / 36, pos = flat % 36;
        size_t pi = ((size_t)(b * 36 + pos)) * 256 + oc;
        float x = pA[pi] + pB[pi] + pcb[oc];
        val[e] = x;
        sn += x * x;
    }
    float scale = sn / ((1.f + sn) * sqrtf(sn));
#pragma unroll
    for (int e = 0; e < 8; ++e) u[(size_t)b * 9216 + flat0 + e] = val[e] * scale;
}

// ---------------- routing ----------------
__global__ void k_softmax(const float* __restrict__ bij, float* __restrict__ cij) {
    __shared__ float red[256];
    int c = blockIdx.x, tid = threadIdx.x;
    float mx = -1e30f;
    for (int r = tid; r < 1152; r += 256) mx = fmaxf(mx, bij[r * 10 + c]);
    red[tid] = mx; __syncthreads();
    for (int s = 128; s > 0; s >>= 1) { if (tid < s) red[tid] = fmaxf(red[tid], red[tid + s]); __syncthreads(); }
    float MX = red[0]; __syncthreads();
    float sm = 0.f;
    for (int r = tid; r < 1152; r += 256) sm += expf(bij[r * 10 + c] - MX);
    red[tid] = sm; __syncthreads();
    for (int s = 128; s > 0; s >>= 1) { if (tid < s) red[tid] += red[tid + s]; __syncthreads(); }
    float inv = 1.f / red[0];
    for (int r = tid; r < 1152; r += 256) cij[r * 10 + c] = expf(bij[r * 10 + c] - MX) * inv;
}

// CW2[k][co] = c[r][c] * W[r][c][o][i] ; k=8r+i, co=16c+o
__global__ void k_fold(const float* __restrict__ cij, const float* __restrict__ W,
                       float* __restrict__ cw2) {
    int idx = blockIdx.x * 256 + threadIdx.x;  // 1474560
    int k = idx / 160, co = idx % 160;
    int r = k >> 3, i = k & 7;
    int c = co >> 4, o = co & 15;
    cw2[idx] = cij[r * 10 + c] * W[((size_t)(r * 10 + c) * 16 + o) * 8 + i];
}

// sPart[kc][b][co] = sum_{k in chunk} u[b][k]*CW2[k][co]; grid 16 btiles x 12 kchunks, 320 thr
__global__ __launch_bounds__(320) void k_sgemm(const float* __restrict__ u,
                                               const float* __restrict__ cw2,
                                               float* __restrict__ sp) {
    __shared__ float ul[32][64];
    int bt = blockIdx.x & 15, kc = blockIdx.x >> 4;
    int b0 = bt * 32, k0 = kc * 768;
    int tid = threadIdx.x;
    int co = tid % 160, half = tid / 160;
    float acc[16];
#pragma unroll
    for (int bb = 0; bb < 16; ++bb) acc[bb] = 0.f;
    for (int kk = 0; kk < 768; kk += 64) {
        for (int i = tid; i < 2048; i += 320)
            ul[i >> 6][i & 63] = u[(size_t)(b0 + (i >> 6)) * 9216 + k0 + kk + (i & 63)];
        __syncthreads();
        for (int kl = 0; kl < 64; ++kl) {
            float w = cw2[(size_t)(k0 + kk + kl) * 160 + co];
#pragma unroll
            for (int bb = 0; bb < 16; ++bb) acc[bb] += ul[half * 16 + bb][kl] * w;
        }
        __syncthreads();
    }
#pragma unroll
    for (int bb = 0; bb < 16; ++bb)
        sp[(size_t)kc * 81920 + (size_t)(b0 + half * 16 + bb) * 160 + co] = acc[bb];
}

// v[b][co] = squash1(sum_p sPart)
__global__ void k_vcomp(const float* __restrict__ sp, float* __restrict__ v) {
    int idx = blockIdx.x * 256 + threadIdx.x;  // 81920
    float s = 0.f;
#pragma unroll
    for (int p = 0; p < 12; ++p) s += sp[(size_t)p * 81920 + idx];
    v[idx] = s * fabsf(s) / (1.f + s * s);
}

// G[k][co] = (1/512) sum_b u[b][k]*v[b][co]; grid 144 k-tiles, 320 thr
__global__ __launch_bounds__(320) void k_ggemm(const float* __restrict__ u,
                                               const float* __restrict__ v,
                                               float* __restrict__ G) {
    __shared__ float ul[64][64];
    int k0 = blockIdx.x * 64;
    int tid = threadIdx.x;
    int co = tid % 160, kh2 = tid / 160;
    float acc[32];
#pragma unroll
    for (int kl = 0; kl < 32; ++kl) acc[kl] = 0.f;
    for (int bc = 0; bc < 512; bc += 64) {
        for (int i = tid; i < 4096; i += 320)
            ul[i >> 6][i & 63] = u[(size_t)(bc + (i >> 6)) * 9216 + k0 + (i & 63)];
        __syncthreads();
        for (int bl = 0; bl < 64; ++bl) {
            float vv = v[(bc + bl) * 160 + co];
#pragma unroll
            for (int kl = 0; kl < 32; ++kl) acc[kl] += ul[bl][kh2 * 32 + kl] * vv;
        }
        __syncthreads();
    }
#pragma unroll
    for (int kl = 0; kl < 32; ++kl)
        G[(size_t)(k0 + kh2 * 32 + kl) * 160 + co] = acc[kl] * (1.0f / 512.0f);
}

// b_ij[r][c] += sum_{i,o} W[r][c][o][i] * G[8r+i][16c+o]
__global__ void k_amean(const float* __restrict__ W, const float* __restrict__ G,
                        float* __restrict__ bij) {
    int idx = blockIdx.x * 256 + threadIdx.x;  // 11520
    if (idx >= 11520) return;
    int r = idx / 10, c = idx % 10;
    float s = 0.f;
    for (int o = 0; o < 16; ++o)
#pragma unroll
        for (int i = 0; i < 8; ++i)
            s += W[((size_t)(r * 10 + c) * 16 + o) * 8 + i] * G[(size_t)(r * 8 + i) * 160 + c * 16 + o];
    bij[idx] += s;
}

// ---------------- encoder ----------------
__global__ void k_enc1(const float* __restrict__ v, const float* __restrict__ w1t,
                       const float* __restrict__ b1, float* __restrict__ h) {
    __shared__ float fl[160];
    int b = blockIdx.x, tid = threadIdx.x;
    if (tid < 160) fl[tid] = v[b * 160 + tid];
    __syncthreads();
    for (int j = tid; j < 512; j += 256) {
        float s = b1[j];
#pragma unroll 8
        for (int k = 0; k < 160; ++k) s += fl[k] * w1t[k * 512 + j];
        h[(size_t)b * 512 + j] = fmaxf(s, 0.f);
    }
}

__global__ void k_enc2(const float* __restrict__ h, const float* __restrict__ w2,
                       const float* __restrict__ b2, float* __restrict__ out) {
    int idx = blockIdx.x * 256 + threadIdx.x;  // 4608
    int b = idx / 9, jj = idx % 9;
    float s = b2[jj];
    for (int k = 0; k < 512; ++k) s += h[(size_t)b * 512 + k] * w2[jj * 512 + k];
    out[idx] = 1.f / (1.f + expf(-s));
}

// ---------------- launch ----------------
extern "C" void kernel_launch(void* const* d_in, const int* in_sizes, int n_in,
                              void* d_out, int out_size, void* d_ws, size_t ws_size,
                              hipStream_t stream) {
    const float* data   = (const float*)d_in[0];
    const float* conv_w = (const float*)d_in[1];
    const float* conv_b = (const float*)d_in[2];
    const float* pc_w   = (const float*)d_in[3];
    const float* pc_b   = (const float*)d_in[4];
    const float* W      = (const float*)d_in[5];
    const float* enc_w1 = (const float*)d_in[6];
    const float* enc_b1 = (const float*)d_in[7];
    const float* enc_w2 = (const float*)d_in[8];
    const float* enc_b2 = (const float*)d_in[9];

    char* ws = (char*)d_ws;
    // total workspace need: 189,622,272 bytes
    bf16_t* xt   = (bf16_t*)(ws + 0);            // 104,857,600
    bf16_t* w2t  = (bf16_t*)(ws + 104857600);    //  10,616,832
    float* partA = (float*)(ws + 115474432);     //  18,874,368
    float* partB = (float*)(ws + 134348800);     //  18,874,368
    float* u     = (float*)(ws + 153223168);     //  18,874,368
    float* cw2   = (float*)(ws + 172097536);     //   5,898,240
    float* G     = (float*)(ws + 177995776);     //   5,898,240
    float* sp    = (float*)(ws + 183894016);     //   3,932,160
    float* v     = (float*)(ws + 187826176);     //     327,680
    float* h     = (float*)(ws + 188153856);     //   1,048,576
    float* w1t   = (float*)(ws + 189202432);     //     327,680
    float* bij   = (float*)(ws + 189530112);     //      46,080
    float* cij   = (float*)(ws + 189576192);     //      46,080
    float* outp  = (float*)d_out;

    hipLaunchKernelGGL(k_init_bij, dim3(45), dim3(256), 0, stream, bij);
    hipLaunchKernelGGL(k_w1t, dim3(320), dim3(256), 0, stream, enc_w1, w1t);
    hipLaunchKernelGGL(k_w2t, dim3(256), dim3(256), 0, stream, pc_w, w2t);
    hipLaunchKernelGGL(k_conv1, dim3(2048), dim3(256), 0, stream, data, conv_w, conv_b, xt);
    hipLaunchKernelGGL(k_pcgemm, dim3(576), dim3(256), 0, stream, xt, w2t, partA, partB);
    hipLaunchKernelGGL(k_squash, dim3(2304), dim3(256), 0, stream, partA, partB, pc_b, u);
    for (int it = 0; it < 3; ++it) {
        hipLaunchKernelGGL(k_softmax, dim3(10), dim3(256), 0, stream, bij, cij);
        hipLaunchKernelGGL(k_fold, dim3(5760), dim3(256), 0, stream, cij, W, cw2);
        hipLaunchKernelGGL(k_sgemm, dim3(192), dim3(320), 0, stream, u, cw2, sp);
        hipLaunchKernelGGL(k_vcomp, dim3(320), dim3(256), 0, stream, sp, v);
        if (it < 2) {
            hipLaunchKernelGGL(k_ggemm, dim3(144), dim3(320), 0, stream, u, v, G);
            hipLaunchKernelGGL(k_amean, dim3(45), dim3(256), 0, stream, W, G, bij);
        }
    }
    hipLaunchKernelGGL(k_enc1, dim3(512), dim3(256), 0, stream, v, w1t, enc_b1, h);
    hipLaunchKernelGGL(k_enc2, dim3(18), dim3(256), 0, stream, h, enc_w2, enc_b2, outp);
}

// Round 2
// 980.498 us; speedup vs baseline: 1.4576x; 1.4576x over previous
//
#include <hip/hip_runtime.h>
#include <hip/hip_bf16.h>
#include <stdint.h>

// CapsNet forward. B=512, conv1 1->256 9x9 s1 (28->20), pc 256->256 9x9 s2 (20->6),
// routes R=1152, caps C=10, I=8, O=16, encoder 160->512->9.

typedef __bf16 bf16_t;
typedef __bf16 bf16x4 __attribute__((ext_vector_type(4)));
typedef __bf16 bf16x8 __attribute__((ext_vector_type(8)));
typedef float f32x4 __attribute__((ext_vector_type(4)));

__device__ __forceinline__ void gload_lds16(const void* g, void* l) {
    __builtin_amdgcn_global_load_lds((const __attribute__((address_space(1))) void*)g,
                                     (__attribute__((address_space(3))) void*)l, 16, 0, 0);
}

// ---------------- prep kernels ----------------
__global__ void k_init_bij(float* bij) {
    int i = blockIdx.x * 256 + threadIdx.x;
    if (i < 1152 * 10) bij[i] = 0.f;
}

// enc_w1 [512][160] -> w1t [160][512]
__global__ void k_w1t(const float* __restrict__ w1, float* __restrict__ w1t) {
    int i = blockIdx.x * 256 + threadIdx.x;  // 81920
    int j = i / 160, k = i % 160;
    w1t[k * 512 + j] = w1[i];
}

// conv_w [256][81] -> cwt [81][256]
__global__ void k_cwt(const float* __restrict__ cw, float* __restrict__ cwt) {
    cwt[blockIdx.x * 256 + threadIdx.x] = cw[threadIdx.x * 81 + blockIdx.x];
}

// pc_w f32 [oc][ic][81] -> W2t bf16 [oc][k] with k = t*256 + ic  (t = kh*9+kw)
__global__ void k_w2t(const float* __restrict__ pcw, bf16_t* __restrict__ w2t) {
    __shared__ bf16_t tmp[20736];
    int oc = blockIdx.x;
    const float* src = pcw + (size_t)oc * 20736;
    for (int q = threadIdx.x; q < 20736; q += 256) {
        int ic = q / 81, t = q % 81;
        tmp[t * 256 + ic] = (bf16_t)src[q];
    }
    __syncthreads();
    bf16_t* dst = w2t + (size_t)oc * 20736;
    for (int q = threadIdx.x; q < 20736; q += 256) dst[q] = tmp[q];
}

// ---------------- conv1 + relu -> x_t NHWC bf16 [b][20][20][256] ----------------
// grid 2048 = 512 b x 4 ocb(64 oc). 320 thr = 16 ocg(4 oc) x 20 oh.
// Image row in registers (sliding window); weights from global cwt[81][256] (L2).
__global__ __launch_bounds__(320) void k_conv1(const float* __restrict__ data,
                                               const float* __restrict__ cwt,
                                               const float* __restrict__ cb,
                                               bf16_t* __restrict__ xt) {
    __shared__ float img[784];
    int b = blockIdx.x >> 2, ocb = blockIdx.x & 3;
    int tid = threadIdx.x;
    for (int i = tid; i < 784; i += 320) img[i] = data[b * 784 + i];
    __syncthreads();
    int ocg = tid & 15, oh = tid >> 4;
    int oc4 = ocb * 64 + ocg * 4;
    f32x4 bias = *(const f32x4*)&cb[oc4];
    f32x4 acc[20];
#pragma unroll
    for (int ow = 0; ow < 20; ++ow) acc[ow] = (f32x4){0.f, 0.f, 0.f, 0.f};
    for (int kh = 0; kh < 9; ++kh) {
        float row[28];
#pragma unroll
        for (int q = 0; q < 7; ++q) {
            f32x4 t = *(const f32x4*)&img[(oh + kh) * 28 + q * 4];
            row[q * 4 + 0] = t.x; row[q * 4 + 1] = t.y;
            row[q * 4 + 2] = t.z; row[q * 4 + 3] = t.w;
        }
#pragma unroll
        for (int kw = 0; kw < 9; ++kw) {
            f32x4 w = *(const f32x4*)&cwt[(kh * 9 + kw) * 256 + oc4];
#pragma unroll
            for (int ow = 0; ow < 20; ++ow) acc[ow] += w * row[ow + kw];
        }
    }
    size_t base = ((size_t)(b * 20 + oh) * 20) * 256 + oc4;
#pragma unroll
    for (int ow = 0; ow < 20; ++ow) {
        f32x4 r = acc[ow] + bias;
        bf16x4 vv;
        vv[0] = (bf16_t)fmaxf(r.x, 0.f);
        vv[1] = (bf16_t)fmaxf(r.y, 0.f);
        vv[2] = (bf16_t)fmaxf(r.z, 0.f);
        vv[3] = (bf16_t)fmaxf(r.w, 0.f);
        *(bf16x4*)&xt[base + (size_t)ow * 256] = vv;
    }
}

// ---------------- PrimaryCaps conv as implicit GEMM, bf16 MFMA ----------------
// C[M=18432][N=256] = A x B ; m=b*36+pos, n=oc, k=(kh*9+kw)*256+ic
// grid 1152 = 144 m-tiles x 2 n-tiles x 4 k-splits ; tile 128x128, BK=64, 81 iters
// LDS XOR-swizzle (chunk ^= row&7) applied on global source + ds_read (rule #21).
__global__ __launch_bounds__(256) void k_pcgemm(const bf16_t* __restrict__ xt,
                                                const bf16_t* __restrict__ w2t,
                                                bf16_t* __restrict__ parts) {
    __shared__ __align__(16) bf16_t As[128 * 64];
    __shared__ __align__(16) bf16_t Bs[128 * 64];
    int bid = blockIdx.x;
    int mt = bid % 144;
    int nt = (bid / 144) & 1;
    int ks = bid / 288;  // 0..3
    int m0 = mt * 128, n0 = nt * 128;
    int tid = threadIdx.x, lane = tid & 63, wave = tid >> 6;

    int csrc = (tid & 7) ^ ((tid >> 3) & 7);  // swizzled source chunk
    int arow[4];
#pragma unroll
    for (int p = 0; p < 4; ++p) {
        int m = m0 + p * 32 + (tid >> 3);
        int bb = m / 36, pos = m % 36;
        int oh = pos / 6, ow = pos % 6;
        arow[p] = ((bb * 20 + oh * 2) * 20 + ow * 2) * 256;
    }
    const bf16_t* bbase = w2t + (size_t)(n0 + (tid >> 3)) * 20736 + csrc * 8;
    bf16_t* aldst = As + tid * 8;
    bf16_t* bldst = Bs + tid * 8;

    f32x4 acc[4][4];
#pragma unroll
    for (int mi = 0; mi < 4; ++mi)
#pragma unroll
        for (int ni = 0; ni < 4; ++ni) acc[mi][ni] = (f32x4){0.f, 0.f, 0.f, 0.f};

    int s0 = ks * 81;
    int t0 = s0 >> 2;
    int icb = s0 & 3;
    int kh = t0 / 9, kw = t0 - (t0 / 9) * 9;

    for (int it = 0; it < 81; ++it) {
        int aoff = (kh * 20 + kw) * 256 + icb * 64 + csrc * 8;
        const bf16_t* bsrc = bbase + (size_t)(s0 + it) * 64;
#pragma unroll
        for (int p = 0; p < 4; ++p) {
            gload_lds16(xt + arow[p] + aoff, aldst + p * 2048);
            gload_lds16(bsrc + (size_t)p * 32 * 20736, bldst + p * 2048);
        }
        __syncthreads();
        int mr = (wave >> 1) * 64 + (lane & 15);
        int nr = (wave & 1) * 64 + (lane & 15);
        int rx = lane & 7;
#pragma unroll
        for (int kk = 0; kk < 2; ++kk) {
            int ch = ((kk * 4 + (lane >> 4)) ^ rx) * 8;  // swizzled read chunk
            bf16x8 af[4], bfr[4];
#pragma unroll
            for (int i = 0; i < 4; ++i) af[i] = *(const bf16x8*)&As[(mr + i * 16) * 64 + ch];
#pragma unroll
            for (int i = 0; i < 4; ++i) bfr[i] = *(const bf16x8*)&Bs[(nr + i * 16) * 64 + ch];
#pragma unroll
            for (int mi = 0; mi < 4; ++mi)
#pragma unroll
                for (int ni = 0; ni < 4; ++ni)
                    acc[mi][ni] = __builtin_amdgcn_mfma_f32_16x16x32_bf16(af[mi], bfr[ni], acc[mi][ni], 0, 0, 0);
        }
        __syncthreads();
        if (++icb == 4) { icb = 0; if (++kw == 9) { kw = 0; ++kh; } }
    }

    bf16_t* out = parts + (size_t)ks * 4718592;
    int mbase = m0 + (wave >> 1) * 64 + (lane >> 4) * 4;
    int nbase = n0 + (wave & 1) * 64 + (lane & 15);
#pragma unroll
    for (int mi = 0; mi < 4; ++mi)
#pragma unroll
        for (int ni = 0; ni < 4; ++ni)
#pragma unroll
            for (int j = 0; j < 4; ++j)
                out[(size_t)(mbase + mi * 16 + j) * 256 + nbase + ni * 16] = (bf16_t)acc[mi][ni][j];
}

// ---------------- squash: 4 bf16 partials + bias -> u[b][flat], flat = oc*36+pos ----------------
// grid 512 (one b per block); stage the b-slice [36*256] into LDS coalesced.
__global__ __launch_bounds__(256) void k_squash(const bf16_t* __restrict__ parts,
                                                const float* __restrict__ pcb,
                                                float* __restrict__ u) {
    __shared__ float s[9216];
    int b = blockIdx.x, tid = threadIdx.x;
    for (int i = tid; i < 9216; i += 256) {
        float a = pcb[i & 255];
#pragma unroll
        for (int p = 0; p < 4; ++p) a += (float)parts[(size_t)p * 4718592 + (size_t)b * 9216 + i];
        s[i] = a;
    }
    __syncthreads();
    for (int r = tid; r < 1152; r += 256) {
        int flat0 = r * 8;
        float val[8], sn = 0.f;
#pragma unroll
        for (int e = 0; e < 8; ++e) {
            int f = flat0 + e;
            float x = s[(f % 36) * 256 + f / 36];
            val[e] = x;
            sn += x * x;
        }
        float scale = sn / ((1.f + sn) * sqrtf(sn));
#pragma unroll
        for (int e = 0; e < 8; ++e) u[(size_t)b * 9216 + flat0 + e] = val[e] * scale;
    }
}

// ---------------- routing ----------------
__global__ void k_softmax(const float* __restrict__ bij, float* __restrict__ cij) {
    __shared__ float red[256];
    int c = blockIdx.x, tid = threadIdx.x;
    float mx = -1e30f;
    for (int r = tid; r < 1152; r += 256) mx = fmaxf(mx, bij[r * 10 + c]);
    red[tid] = mx; __syncthreads();
    for (int s = 128; s > 0; s >>= 1) { if (tid < s) red[tid] = fmaxf(red[tid], red[tid + s]); __syncthreads(); }
    float MX = red[0]; __syncthreads();
    float sm = 0.f;
    for (int r = tid; r < 1152; r += 256) sm += expf(bij[r * 10 + c] - MX);
    red[tid] = sm; __syncthreads();
    for (int s = 128; s > 0; s >>= 1) { if (tid < s) red[tid] += red[tid + s]; __syncthreads(); }
    float inv = 1.f / red[0];
    for (int r = tid; r < 1152; r += 256) cij[r * 10 + c] = expf(bij[r * 10 + c] - MX) * inv;
}

// CW2[k][co] = c[r][c] * W[r][c][o][i] ; k=8r+i, co=16c+o
__global__ void k_fold(const float* __restrict__ cij, const float* __restrict__ W,
                       float* __restrict__ cw2) {
    int idx = blockIdx.x * 256 + threadIdx.x;  // 1474560
    int k = idx / 160, co = idx % 160;
    int r = k >> 3, i = k & 7;
    int c = co >> 4, o = co & 15;
    cw2[idx] = cij[r * 10 + c] * W[((size_t)(r * 10 + c) * 16 + o) * 8 + i];
}

// sPart[kc][b][co] = sum_{k in chunk} u[b][k]*CW2[k][co]; grid 32 btiles x 12 kchunks, 320 thr
__global__ __launch_bounds__(320) void k_sgemm(const float* __restrict__ u,
                                               const float* __restrict__ cw2,
                                               float* __restrict__ sp) {
    __shared__ float ul[16][64];
    int bt = blockIdx.x & 31, kc = blockIdx.x >> 5;
    int b0 = bt * 16, k0 = kc * 768;
    int tid = threadIdx.x;
    int co = tid % 160, half = tid / 160;
    float acc[8];
#pragma unroll
    for (int bb = 0; bb < 8; ++bb) acc[bb] = 0.f;
    for (int kk = 0; kk < 768; kk += 64) {
        for (int i = tid; i < 1024; i += 320)
            ul[i >> 6][i & 63] = u[(size_t)(b0 + (i >> 6)) * 9216 + k0 + kk + (i & 63)];
        __syncthreads();
        for (int kl = 0; kl < 64; ++kl) {
            float w = cw2[(size_t)(k0 + kk + kl) * 160 + co];
#pragma unroll
            for (int bb = 0; bb < 8; ++bb) acc[bb] += ul[half * 8 + bb][kl] * w;
        }
        __syncthreads();
    }
#pragma unroll
    for (int bb = 0; bb < 8; ++bb)
        sp[(size_t)kc * 81920 + (size_t)(b0 + half * 8 + bb) * 160 + co] = acc[bb];
}

// v[b][co] = squash1(sum_p sPart)
__global__ void k_vcomp(const float* __restrict__ sp, float* __restrict__ v) {
    int idx = blockIdx.x * 256 + threadIdx.x;  // 81920
    float s = 0.f;
#pragma unroll
    for (int p = 0; p < 12; ++p) s += sp[(size_t)p * 81920 + idx];
    v[idx] = s * fabsf(s) / (1.f + s * s);
}

// G[k][co] = (1/512) sum_b u[b][k]*v[b][co]; grid 144 k-tiles, 320 thr
__global__ __launch_bounds__(320) void k_ggemm(const float* __restrict__ u,
                                               const float* __restrict__ v,
                                               float* __restrict__ G) {
    __shared__ float ul[64][64];
    int k0 = blockIdx.x * 64;
    int tid = threadIdx.x;
    int co = tid % 160, kh2 = tid / 160;
    float acc[32];
#pragma unroll
    for (int kl = 0; kl < 32; ++kl) acc[kl] = 0.f;
    for (int bc = 0; bc < 512; bc += 64) {
        for (int i = tid; i < 4096; i += 320)
            ul[i >> 6][i & 63] = u[(size_t)(bc + (i >> 6)) * 9216 + k0 + (i & 63)];
        __syncthreads();
        for (int bl = 0; bl < 64; ++bl) {
            float vv = v[(bc + bl) * 160 + co];
#pragma unroll
            for (int kl = 0; kl < 32; ++kl) acc[kl] += ul[bl][kh2 * 32 + kl] * vv;
        }
        __syncthreads();
    }
#pragma unroll
    for (int kl = 0; kl < 32; ++kl)
        G[(size_t)(k0 + kh2 * 32 + kl) * 160 + co] = acc[kl] * (1.0f / 512.0f);
}

// b_ij[r][c] += sum_{i,o} W[r][c][o][i] * G[8r+i][16c+o]
__global__ void k_amean(const float* __restrict__ W, const float* __restrict__ G,
                        float* __restrict__ bij) {
    int idx = blockIdx.x * 256 + threadIdx.x;  // 11520
    if (idx >= 11520) return;
    int r = idx / 10, c = idx % 10;
    float s = 0.f;
    for (int o = 0; o < 16; ++o)
#pragma unroll
        for (int i = 0; i < 8; ++i)
            s += W[((size_t)(r * 10 + c) * 16 + o) * 8 + i] * G[(size_t)(r * 8 + i) * 160 + c * 16 + o];
    bij[idx] += s;
}

// ---------------- encoder ----------------
__global__ void k_enc1(const float* __restrict__ v, const float* __restrict__ w1t,
                       const float* __restrict__ b1, float* __restrict__ h) {
    __shared__ float fl[160];
    int b = blockIdx.x, tid = threadIdx.x;
    if (tid < 160) fl[tid] = v[b * 160 + tid];
    __syncthreads();
    for (int j = tid; j < 512; j += 256) {
        float s = b1[j];
#pragma unroll 8
        for (int k = 0; k < 160; ++k) s += fl[k] * w1t[k * 512 + j];
        h[(size_t)b * 512 + j] = fmaxf(s, 0.f);
    }
}

__global__ void k_enc2(const float* __restrict__ h, const float* __restrict__ w2,
                       const float* __restrict__ b2, float* __restrict__ out) {
    int idx = blockIdx.x * 256 + threadIdx.x;  // 4608
    int b = idx / 9, jj = idx % 9;
    float s = b2[jj];
    for (int k = 0; k < 512; ++k) s += h[(size_t)b * 512 + k] * w2[jj * 512 + k];
    out[idx] = 1.f / (1.f + expf(-s));
}

// ---------------- launch ----------------
extern "C" void kernel_launch(void* const* d_in, const int* in_sizes, int n_in,
                              void* d_out, int out_size, void* d_ws, size_t ws_size,
                              hipStream_t stream) {
    const float* data   = (const float*)d_in[0];
    const float* conv_w = (const float*)d_in[1];
    const float* conv_b = (const float*)d_in[2];
    const float* pc_w   = (const float*)d_in[3];
    const float* pc_b   = (const float*)d_in[4];
    const float* W      = (const float*)d_in[5];
    const float* enc_w1 = (const float*)d_in[6];
    const float* enc_b1 = (const float*)d_in[7];
    const float* enc_w2 = (const float*)d_in[8];
    const float* enc_b2 = (const float*)d_in[9];

    char* ws = (char*)d_ws;
    // workspace map (total ~189.7 MB)
    bf16_t* xt    = (bf16_t*)(ws + 0);            // 104,857,600
    bf16_t* w2t   = (bf16_t*)(ws + 104857600);    //  10,616,832
    bf16_t* parts = (bf16_t*)(ws + 115474432);    //  37,748,736 (4 x 4,718,592 elems bf16)
    float* u      = (float*)(ws + 153223168);     //  18,874,368
    float* cw2    = (float*)(ws + 172097536);     //   5,898,240
    float* G      = (float*)(ws + 177995776);     //   5,898,240
    float* sp     = (float*)(ws + 183894016);     //   3,932,160
    float* v      = (float*)(ws + 187826176);     //     327,680
    float* h      = (float*)(ws + 188153856);     //   1,048,576
    float* w1t    = (float*)(ws + 189202432);     //     327,680
    float* bij    = (float*)(ws + 189530112);     //      46,080
    float* cij    = (float*)(ws + 189576192);     //      46,080
    float* cwt    = (float*)(ws + 189622272);     //      82,944
    float* outp   = (float*)d_out;

    hipLaunchKernelGGL(k_init_bij, dim3(45), dim3(256), 0, stream, bij);
    hipLaunchKernelGGL(k_w1t, dim3(320), dim3(256), 0, stream, enc_w1, w1t);
    hipLaunchKernelGGL(k_cwt, dim3(81), dim3(256), 0, stream, conv_w, cwt);
    hipLaunchKernelGGL(k_w2t, dim3(256), dim3(256), 0, stream, pc_w, w2t);
    hipLaunchKernelGGL(k_conv1, dim3(2048), dim3(320), 0, stream, data, cwt, conv_b, xt);
    hipLaunchKernelGGL(k_pcgemm, dim3(1152), dim3(256), 0, stream, xt, w2t, parts);
    hipLaunchKernelGGL(k_squash, dim3(512), dim3(256), 0, stream, parts, pc_b, u);
    for (int it = 0; it < 3; ++it) {
        hipLaunchKernelGGL(k_softmax, dim3(10), dim3(256), 0, stream, bij, cij);
        hipLaunchKernelGGL(k_fold, dim3(5760), dim3(256), 0, stream, cij, W, cw2);
        hipLaunchKernelGGL(k_sgemm, dim3(384), dim3(320), 0, stream, u, cw2, sp);
        hipLaunchKernelGGL(k_vcomp, dim3(320), dim3(256), 0, stream, sp, v);
        if (it < 2) {
            hipLaunchKernelGGL(k_ggemm, dim3(144), dim3(320), 0, stream, u, v, G);
            hipLaunchKernelGGL(k_amean, dim3(45), dim3(256), 0, stream, W, G, bij);
        }
    }
    hipLaunchKernelGGL(k_enc1, dim3(512), dim3(256), 0, stream, v, w1t, enc_b1, h);
    hipLaunchKernelGGL(k_enc2, dim3(18), dim3(256), 0, stream, h, enc_w2, enc_b2, outp);
}

// Round 3
// 560.645 us; speedup vs baseline: 2.5491x; 1.7489x over previous
//
#include <hip/hip_runtime.h>
#include <hip/hip_bf16.h>
#include <stdint.h>

// CapsNet forward. B=512, conv1 1->256 9x9 s1 (28->20), pc 256->256 9x9 s2 (20->6),
// routes R=1152, caps C=10, I=8, O=16, encoder 160->512->9.

typedef __bf16 bf16_t;
typedef __bf16 bf16x4 __attribute__((ext_vector_type(4)));
typedef __bf16 bf16x8 __attribute__((ext_vector_type(8)));
typedef float f32x4 __attribute__((ext_vector_type(4)));

__device__ __forceinline__ void gload_lds16(const void* g, void* l) {
    __builtin_amdgcn_global_load_lds((const __attribute__((address_space(1))) void*)g,
                                     (__attribute__((address_space(3))) void*)l, 16, 0, 0);
}

// ---------------- prep kernels ----------------
__global__ void k_init_bij(float* bij) {
    int i = blockIdx.x * 256 + threadIdx.x;
    if (i < 1152 * 10) bij[i] = 0.f;
}

// enc_w1 [512][160] -> w1t [160][512]
__global__ void k_w1t(const float* __restrict__ w1, float* __restrict__ w1t) {
    int i = blockIdx.x * 256 + threadIdx.x;  // 81920
    int j = i / 160, k = i % 160;
    w1t[k * 512 + j] = w1[i];
}

// conv_w [256][81] -> cwt [81][256]
__global__ void k_cwt(const float* __restrict__ cw, float* __restrict__ cwt) {
    cwt[blockIdx.x * 256 + threadIdx.x] = cw[threadIdx.x * 81 + blockIdx.x];
}

// pc_w f32 [oc][ic][81] -> W2t bf16 [oc][k] with k = t*256 + ic  (t = kh*9+kw)
__global__ void k_w2t(const float* __restrict__ pcw, bf16_t* __restrict__ w2t) {
    __shared__ bf16_t tmp[20736];
    int oc = blockIdx.x;
    const float* src = pcw + (size_t)oc * 20736;
    for (int q = threadIdx.x; q < 20736; q += 256) {
        int ic = q / 81, t = q % 81;
        tmp[t * 256 + ic] = (bf16_t)src[q];
    }
    __syncthreads();
    bf16_t* dst = w2t + (size_t)oc * 20736;
    for (int q = threadIdx.x; q < 20736; q += 256) dst[q] = tmp[q];
}

// ---------------- conv1 + relu -> x_t NHWC bf16 [b][20][20][256] ----------------
__global__ __launch_bounds__(320) void k_conv1(const float* __restrict__ data,
                                               const float* __restrict__ cwt,
                                               const float* __restrict__ cb,
                                               bf16_t* __restrict__ xt) {
    __shared__ float img[784];
    int b = blockIdx.x >> 2, ocb = blockIdx.x & 3;
    int tid = threadIdx.x;
    for (int i = tid; i < 784; i += 320) img[i] = data[b * 784 + i];
    __syncthreads();
    int ocg = tid & 15, oh = tid >> 4;
    int oc4 = ocb * 64 + ocg * 4;
    f32x4 bias = *(const f32x4*)&cb[oc4];
    f32x4 acc[20];
#pragma unroll
    for (int ow = 0; ow < 20; ++ow) acc[ow] = (f32x4){0.f, 0.f, 0.f, 0.f};
    for (int kh = 0; kh < 9; ++kh) {
        float row[28];
#pragma unroll
        for (int q = 0; q < 7; ++q) {
            f32x4 t = *(const f32x4*)&img[(oh + kh) * 28 + q * 4];
            row[q * 4 + 0] = t.x; row[q * 4 + 1] = t.y;
            row[q * 4 + 2] = t.z; row[q * 4 + 3] = t.w;
        }
#pragma unroll
        for (int kw = 0; kw < 9; ++kw) {
            f32x4 w = *(const f32x4*)&cwt[(kh * 9 + kw) * 256 + oc4];
#pragma unroll
            for (int ow = 0; ow < 20; ++ow) acc[ow] += w * row[ow + kw];
        }
    }
    size_t base = ((size_t)(b * 20 + oh) * 20) * 256 + oc4;
#pragma unroll
    for (int ow = 0; ow < 20; ++ow) {
        f32x4 r = acc[ow] + bias;
        bf16x4 vv;
        vv[0] = (bf16_t)fmaxf(r.x, 0.f);
        vv[1] = (bf16_t)fmaxf(r.y, 0.f);
        vv[2] = (bf16_t)fmaxf(r.z, 0.f);
        vv[3] = (bf16_t)fmaxf(r.w, 0.f);
        *(bf16x4*)&xt[base + (size_t)ow * 256] = vv;
    }
}

// ---------------- PrimaryCaps conv as implicit GEMM, bf16 MFMA ----------------
// grid 1152 = 144 m-tiles x 2 n-tiles x 4 k-splits ; tile 128x128, BK=64, 81 iters
__global__ __launch_bounds__(256) void k_pcgemm(const bf16_t* __restrict__ xt,
                                                const bf16_t* __restrict__ w2t,
                                                bf16_t* __restrict__ parts) {
    __shared__ __align__(16) bf16_t As[128 * 64];
    __shared__ __align__(16) bf16_t Bs[128 * 64];
    int bid = blockIdx.x;
    int mt = bid % 144;
    int nt = (bid / 144) & 1;
    int ks = bid / 288;  // 0..3
    int m0 = mt * 128, n0 = nt * 128;
    int tid = threadIdx.x, lane = tid & 63, wave = tid >> 6;

    int csrc = (tid & 7) ^ ((tid >> 3) & 7);  // swizzled source chunk
    int arow[4];
#pragma unroll
    for (int p = 0; p < 4; ++p) {
        int m = m0 + p * 32 + (tid >> 3);
        int bb = m / 36, pos = m % 36;
        int oh = pos / 6, ow = pos % 6;
        arow[p] = ((bb * 20 + oh * 2) * 20 + ow * 2) * 256;
    }
    const bf16_t* bbase = w2t + (size_t)(n0 + (tid >> 3)) * 20736 + csrc * 8;
    bf16_t* aldst = As + tid * 8;
    bf16_t* bldst = Bs + tid * 8;

    f32x4 acc[4][4];
#pragma unroll
    for (int mi = 0; mi < 4; ++mi)
#pragma unroll
        for (int ni = 0; ni < 4; ++ni) acc[mi][ni] = (f32x4){0.f, 0.f, 0.f, 0.f};

    int s0 = ks * 81;
    int t0 = s0 >> 2;
    int icb = s0 & 3;
    int kh = t0 / 9, kw = t0 - (t0 / 9) * 9;

    for (int it = 0; it < 81; ++it) {
        int aoff = (kh * 20 + kw) * 256 + icb * 64 + csrc * 8;
        const bf16_t* bsrc = bbase + (size_t)(s0 + it) * 64;
#pragma unroll
        for (int p = 0; p < 4; ++p) {
            gload_lds16(xt + arow[p] + aoff, aldst + p * 2048);
            gload_lds16(bsrc + (size_t)p * 32 * 20736, bldst + p * 2048);
        }
        __syncthreads();
        int mr = (wave >> 1) * 64 + (lane & 15);
        int nr = (wave & 1) * 64 + (lane & 15);
        int rx = lane & 7;
#pragma unroll
        for (int kk = 0; kk < 2; ++kk) {
            int ch = ((kk * 4 + (lane >> 4)) ^ rx) * 8;  // swizzled read chunk
            bf16x8 af[4], bfr[4];
#pragma unroll
            for (int i = 0; i < 4; ++i) af[i] = *(const bf16x8*)&As[(mr + i * 16) * 64 + ch];
#pragma unroll
            for (int i = 0; i < 4; ++i) bfr[i] = *(const bf16x8*)&Bs[(nr + i * 16) * 64 + ch];
#pragma unroll
            for (int mi = 0; mi < 4; ++mi)
#pragma unroll
                for (int ni = 0; ni < 4; ++ni)
                    acc[mi][ni] = __builtin_amdgcn_mfma_f32_16x16x32_bf16(af[mi], bfr[ni], acc[mi][ni], 0, 0, 0);
        }
        __syncthreads();
        if (++icb == 4) { icb = 0; if (++kw == 9) { kw = 0; ++kh; } }
    }

    bf16_t* out = parts + (size_t)ks * 4718592;
    int mbase = m0 + (wave >> 1) * 64 + (lane >> 4) * 4;
    int nbase = n0 + (wave & 1) * 64 + (lane & 15);
#pragma unroll
    for (int mi = 0; mi < 4; ++mi)
#pragma unroll
        for (int ni = 0; ni < 4; ++ni)
#pragma unroll
            for (int j = 0; j < 4; ++j)
                out[(size_t)(mbase + mi * 16 + j) * 256 + nbase + ni * 16] = (bf16_t)acc[mi][ni][j];
}

// ---------------- squash -> u bf16 [b][flat], flat = oc*36+pos ----------------
__global__ __launch_bounds__(256) void k_squash(const bf16_t* __restrict__ parts,
                                                const float* __restrict__ pcb,
                                                bf16_t* __restrict__ ub) {
    __shared__ float s[9216];
    int b = blockIdx.x, tid = threadIdx.x;
    for (int i = tid; i < 9216; i += 256) {
        float a = pcb[i & 255];
#pragma unroll
        for (int p = 0; p < 4; ++p) a += (float)parts[(size_t)p * 4718592 + (size_t)b * 9216 + i];
        s[i] = a;
    }
    __syncthreads();
    for (int r = tid; r < 1152; r += 256) {
        int flat0 = r * 8;
        float val[8], sn = 0.f;
#pragma unroll
        for (int e = 0; e < 8; ++e) {
            int f = flat0 + e;
            float x = s[(f % 36) * 256 + f / 36];
            val[e] = x;
            sn += x * x;
        }
        float scale = sn / ((1.f + sn) * sqrtf(sn));
        bf16x8 vv;
#pragma unroll
        for (int e = 0; e < 8; ++e) vv[e] = (bf16_t)(val[e] * scale);
        *(bf16x8*)&ub[(size_t)b * 9216 + flat0] = vv;
    }
}

// ---------------- u bf16 [512][9216] -> uT bf16 [9216][512] ----------------
// grid 1152 = 144 k-tiles x 8 b-tiles; LDS tile 64x64, pad 66.
__global__ __launch_bounds__(256) void k_uT(const bf16_t* __restrict__ ub, bf16_t* __restrict__ uT) {
    __shared__ bf16_t t[64 * 66];
    int kt = blockIdx.x % 144, bt = blockIdx.x / 144;
    int k0 = kt * 64, b0 = bt * 64;
    int tid = threadIdx.x;
    int c8 = tid & 7;
#pragma unroll
    for (int p = 0; p < 2; ++p) {
        int r = p * 32 + (tid >> 3);  // b-local
        bf16x8 vv = *(const bf16x8*)&ub[(size_t)(b0 + r) * 9216 + k0 + c8 * 8];
        uint32_t u4[4];
        *(bf16x8*)u4 = vv;
#pragma unroll
        for (int j2 = 0; j2 < 4; ++j2)
            *(uint32_t*)&t[r * 66 + c8 * 8 + j2 * 2] = u4[j2];
    }
    __syncthreads();
#pragma unroll
    for (int p = 0; p < 2; ++p) {
        int kp = p * 32 + (tid >> 3);  // k-local
        bf16x8 vv;
#pragma unroll
        for (int j = 0; j < 8; ++j) vv[j] = t[(c8 * 8 + j) * 66 + kp];
        *(bf16x8*)&uT[(size_t)(k0 + kp) * 512 + b0 + c8 * 8] = vv;
    }
}

// ---------------- v f32 [512][160] -> vT bf16 [160][512] ----------------
// grid 40 = 5 co-tiles(32) x 8 b-tiles(64); LDS f32 [32][65].
__global__ __launch_bounds__(256) void k_vt(const float* __restrict__ v, bf16_t* __restrict__ vT) {
    __shared__ float tf[32 * 65];
    int ct = blockIdx.x % 5, bt = blockIdx.x / 5;
    int c0 = ct * 32, b0 = bt * 64;
    int tid = threadIdx.x;
    for (int i = tid; i < 2048; i += 256) {
        int r = i >> 5, c = i & 31;
        tf[c * 65 + r] = v[(size_t)(b0 + r) * 160 + c0 + c];
    }
    __syncthreads();
    for (int i = tid; i < 2048; i += 256) {
        int c = i >> 6, r = i & 63;
        vT[(size_t)(c0 + c) * 512 + b0 + r] = (bf16_t)tf[c * 65 + r];
    }
}

// ---------------- shared NT MFMA kernel: C[M][160] = A[M][K] x B[160][K]^T ----------------
// grid = mtiles * ksplit, 256 thr; tile 64x160, BK=64; partials Cp[ks][M][160] f32.
__global__ __launch_bounds__(256) void k_rgemm(const bf16_t* __restrict__ A,
                                               const bf16_t* __restrict__ B,
                                               float* __restrict__ Cp,
                                               int Kfull, int steps, int mtiles) {
    __shared__ __align__(16) bf16_t As[64 * 64];
    __shared__ __align__(16) bf16_t Bs[160 * 64];
    int bid = blockIdx.x;
    int mt = bid % mtiles, ks = bid / mtiles;
    int m0 = mt * 64;
    int k0 = ks * steps * 64;
    int tid = threadIdx.x, lane = tid & 63, wave = tid >> 6;
    int srow = tid >> 3;                       // 0..31
    int csrc = (tid & 7) ^ (srow & 7);
    const bf16_t* asrc[2];
    const bf16_t* bsrc[5];
#pragma unroll
    for (int p = 0; p < 2; ++p)
        asrc[p] = A + (size_t)(m0 + p * 32 + srow) * Kfull + k0 + csrc * 8;
#pragma unroll
    for (int p = 0; p < 5; ++p)
        bsrc[p] = B + (size_t)(p * 32 + srow) * Kfull + k0 + csrc * 8;

    f32x4 acc[2][5];
#pragma unroll
    for (int mi = 0; mi < 2; ++mi)
#pragma unroll
        for (int nj = 0; nj < 5; ++nj) acc[mi][nj] = (f32x4){0.f, 0.f, 0.f, 0.f};

    int mr = (wave >> 1) * 32 + (lane & 15);
    int nr = (wave & 1) * 80 + (lane & 15);
    int rx = lane & 7;

    for (int it = 0; it < steps; ++it) {
#pragma unroll
        for (int p = 0; p < 2; ++p) gload_lds16(asrc[p] + it * 64, As + p * 2048 + tid * 8);
#pragma unroll
        for (int p = 0; p < 5; ++p) gload_lds16(bsrc[p] + it * 64, Bs + p * 2048 + tid * 8);
        __syncthreads();
#pragma unroll
        for (int kk = 0; kk < 2; ++kk) {
            int ch = ((kk * 4 + (lane >> 4)) ^ rx) * 8;
            bf16x8 af[2], bfr[5];
#pragma unroll
            for (int i = 0; i < 2; ++i) af[i] = *(const bf16x8*)&As[(mr + i * 16) * 64 + ch];
#pragma unroll
            for (int j = 0; j < 5; ++j) bfr[j] = *(const bf16x8*)&Bs[(nr + j * 16) * 64 + ch];
#pragma unroll
            for (int mi = 0; mi < 2; ++mi)
#pragma unroll
                for (int nj = 0; nj < 5; ++nj)
                    acc[mi][nj] = __builtin_amdgcn_mfma_f32_16x16x32_bf16(af[mi], bfr[nj], acc[mi][nj], 0, 0, 0);
        }
        __syncthreads();
    }

    float* out = Cp + (size_t)ks * ((size_t)mtiles * 64 * 160);
    int mbase = m0 + (wave >> 1) * 32 + (lane >> 4) * 4;
    int nbase = (wave & 1) * 80 + (lane & 15);
#pragma unroll
    for (int mi = 0; mi < 2; ++mi)
#pragma unroll
        for (int nj = 0; nj < 5; ++nj)
#pragma unroll
            for (int j = 0; j < 4; ++j)
                out[(size_t)(mbase + mi * 16 + j) * 160 + nbase + nj * 16] = acc[mi][nj][j];
}

// ---------------- routing glue ----------------
__global__ void k_softmax(const float* __restrict__ bij, float* __restrict__ cij) {
    __shared__ float red[256];
    int c = blockIdx.x, tid = threadIdx.x;
    float mx = -1e30f;
    for (int r = tid; r < 1152; r += 256) mx = fmaxf(mx, bij[r * 10 + c]);
    red[tid] = mx; __syncthreads();
    for (int s = 128; s > 0; s >>= 1) { if (tid < s) red[tid] = fmaxf(red[tid], red[tid + s]); __syncthreads(); }
    float MX = red[0]; __syncthreads();
    float sm = 0.f;
    for (int r = tid; r < 1152; r += 256) sm += expf(bij[r * 10 + c] - MX);
    red[tid] = sm; __syncthreads();
    for (int s = 128; s > 0; s >>= 1) { if (tid < s) red[tid] += red[tid + s]; __syncthreads(); }
    float inv = 1.f / red[0];
    for (int r = tid; r < 1152; r += 256) cij[r * 10 + c] = expf(bij[r * 10 + c] - MX) * inv;
}

// cw2T bf16 [co=160][k=9216]: cw2T[co][k] = c[r][c]*W[r][c][o][i], k=8r+i, co=16c+o
__global__ void k_fold(const float* __restrict__ cij, const float* __restrict__ W,
                       bf16_t* __restrict__ cw2T) {
    int idx = blockIdx.x * 256 + threadIdx.x;  // 1474560
    int co = idx / 9216, k = idx % 9216;
    int r = k >> 3, i = k & 7;
    int c = co >> 4, o = co & 15;
    cw2T[idx] = (bf16_t)(cij[r * 10 + c] * W[((size_t)(r * 10 + c) * 16 + o) * 8 + i]);
}

// v[b][co] = squash1(sum_{ks<36} sp)
__global__ void k_vcomp(const float* __restrict__ sp, float* __restrict__ v) {
    int idx = blockIdx.x * 256 + threadIdx.x;  // 81920
    float s = 0.f;
#pragma unroll
    for (int p = 0; p < 36; ++p) s += sp[(size_t)p * 81920 + idx];
    v[idx] = s * fabsf(s) / (1.f + s * s);
}

// b_ij[r][c] += (1/512) sum_{i,o} W[r][c][o][i] * (Gp0+Gp1)[8r+i][16c+o]
__global__ void k_amean(const float* __restrict__ W, const float* __restrict__ Gp,
                        float* __restrict__ bij) {
    int idx = blockIdx.x * 256 + threadIdx.x;  // 11520
    if (idx >= 11520) return;
    int r = idx / 10, c = idx % 10;
    float s = 0.f;
    for (int o = 0; o < 16; ++o)
#pragma unroll
        for (int i = 0; i < 8; ++i) {
            size_t gi = (size_t)(r * 8 + i) * 160 + c * 16 + o;
            s += W[((size_t)(r * 10 + c) * 16 + o) * 8 + i] * (Gp[gi] + Gp[1474560 + gi]);
        }
    bij[idx] += s * (1.0f / 512.0f);
}

// ---------------- encoder ----------------
__global__ void k_enc1(const float* __restrict__ v, const float* __restrict__ w1t,
                       const float* __restrict__ b1, float* __restrict__ h) {
    __shared__ float fl[160];
    int b = blockIdx.x, tid = threadIdx.x;
    if (tid < 160) fl[tid] = v[b * 160 + tid];
    __syncthreads();
    for (int j = tid; j < 512; j += 256) {
        float s = b1[j];
#pragma unroll 8
        for (int k = 0; k < 160; ++k) s += fl[k] * w1t[k * 512 + j];
        h[(size_t)b * 512 + j] = fmaxf(s, 0.f);
    }
}

__global__ void k_enc2(const float* __restrict__ h, const float* __restrict__ w2,
                       const float* __restrict__ b2, float* __restrict__ out) {
    int idx = blockIdx.x * 256 + threadIdx.x;  // 4608
    int b = idx / 9, jj = idx % 9;
    float s = b2[jj];
    for (int k = 0; k < 512; ++k) s += h[(size_t)b * 512 + k] * w2[jj * 512 + k];
    out[idx] = 1.f / (1.f + expf(-s));
}

// ---------------- launch ----------------
extern "C" void kernel_launch(void* const* d_in, const int* in_sizes, int n_in,
                              void* d_out, int out_size, void* d_ws, size_t ws_size,
                              hipStream_t stream) {
    const float* data   = (const float*)d_in[0];
    const float* conv_w = (const float*)d_in[1];
    const float* conv_b = (const float*)d_in[2];
    const float* pc_w   = (const float*)d_in[3];
    const float* pc_b   = (const float*)d_in[4];
    const float* W      = (const float*)d_in[5];
    const float* enc_w1 = (const float*)d_in[6];
    const float* enc_b1 = (const float*)d_in[7];
    const float* enc_w2 = (const float*)d_in[8];
    const float* enc_b2 = (const float*)d_in[9];

    char* ws = (char*)d_ws;
    bf16_t* xt    = (bf16_t*)(ws + 0);            // 104,857,600
    bf16_t* w2t   = (bf16_t*)(ws + 104857600);    //  10,616,832 -> 115,474,432
    bf16_t* parts = (bf16_t*)(ws + 115474432);    //  37,748,736 -> 153,223,168
    // overlay inside parts region (all used only after k_squash consumed parts):
    bf16_t* uT    = (bf16_t*)(ws + 115474432);    //   9,437,184
    bf16_t* cw2T  = (bf16_t*)(ws + 124911616);    //   2,949,120
    float*  sp    = (float*)(ws + 127860736);     //  11,796,480
    float*  Gp    = (float*)(ws + 139657216);     //  11,796,480 -> 151,453,696 (<153,223,168 OK)
    bf16_t* ub    = (bf16_t*)(ws + 153223168);    //   9,437,184 -> 162,660,352
    float*  v     = (float*)(ws + 162660352);     //     327,680
    bf16_t* vT    = (bf16_t*)(ws + 162988032);    //     163,840
    float*  h     = (float*)(ws + 163151872);     //   1,048,576
    float*  w1t   = (float*)(ws + 164200448);     //     327,680
    float*  bij   = (float*)(ws + 164528128);     //      46,080
    float*  cij   = (float*)(ws + 164574208);     //      46,080
    float*  cwt   = (float*)(ws + 164620288);     //      82,944  -> 164,703,232 total
    float*  outp  = (float*)d_out;

    hipLaunchKernelGGL(k_init_bij, dim3(45), dim3(256), 0, stream, bij);
    hipLaunchKernelGGL(k_w1t, dim3(320), dim3(256), 0, stream, enc_w1, w1t);
    hipLaunchKernelGGL(k_cwt, dim3(81), dim3(256), 0, stream, conv_w, cwt);
    hipLaunchKernelGGL(k_w2t, dim3(256), dim3(256), 0, stream, pc_w, w2t);
    hipLaunchKernelGGL(k_conv1, dim3(2048), dim3(320), 0, stream, data, cwt, conv_b, xt);
    hipLaunchKernelGGL(k_pcgemm, dim3(1152), dim3(256), 0, stream, xt, w2t, parts);
    hipLaunchKernelGGL(k_squash, dim3(512), dim3(256), 0, stream, parts, pc_b, ub);
    hipLaunchKernelGGL(k_uT, dim3(1152), dim3(256), 0, stream, ub, uT);
    for (int it = 0; it < 3; ++it) {
        hipLaunchKernelGGL(k_softmax, dim3(10), dim3(256), 0, stream, bij, cij);
        hipLaunchKernelGGL(k_fold, dim3(5760), dim3(256), 0, stream, cij, W, cw2T);
        // s partials: A=ub [512][9216], B=cw2T [160][9216]; mtiles=8, ksplit=36, steps=4
        hipLaunchKernelGGL(k_rgemm, dim3(288), dim3(256), 0, stream, ub, cw2T, sp, 9216, 4, 8);
        hipLaunchKernelGGL(k_vcomp, dim3(320), dim3(256), 0, stream, sp, v);
        if (it < 2) {
            hipLaunchKernelGGL(k_vt, dim3(40), dim3(256), 0, stream, v, vT);
            // G partials: A=uT [9216][512], B=vT [160][512]; mtiles=144, ksplit=2, steps=4
            hipLaunchKernelGGL(k_rgemm, dim3(288), dim3(256), 0, stream, uT, vT, Gp, 512, 4, 144);
            hipLaunchKernelGGL(k_amean, dim3(45), dim3(256), 0, stream, W, Gp, bij);
        }
    }
    hipLaunchKernelGGL(k_enc1, dim3(512), dim3(256), 0, stream, v, w1t, enc_b1, h);
    hipLaunchKernelGGL(k_enc2, dim3(18), dim3(256), 0, stream, h, enc_w2, enc_b2, outp);
}

// Round 4
// 547.098 us; speedup vs baseline: 2.6123x; 1.0248x over previous
//
#include <hip/hip_runtime.h>
#include <hip/hip_bf16.h>
#include <stdint.h>

// CapsNet forward. B=512, conv1 1->256 9x9 s1 (28->20), pc 256->256 9x9 s2 (20->6),
// routes R=1152, caps C=10, I=8, O=16, encoder 160->512->9.

typedef __bf16 bf16_t;
typedef __bf16 bf16x4 __attribute__((ext_vector_type(4)));
typedef __bf16 bf16x8 __attribute__((ext_vector_type(8)));
typedef float f32x4 __attribute__((ext_vector_type(4)));

__device__ __forceinline__ void gload_lds16(const void* g, void* l) {
    __builtin_amdgcn_global_load_lds((const __attribute__((address_space(1))) void*)g,
                                     (__attribute__((address_space(3))) void*)l, 16, 0, 0);
}

#define MEMBAR() asm volatile("" ::: "memory")
#define HW_BARRIER() do { MEMBAR(); __builtin_amdgcn_s_barrier(); MEMBAR(); } while (0)

// ---------------- prep kernels ----------------
__global__ void k_init_bij(float* bij) {
    int i = blockIdx.x * 256 + threadIdx.x;
    if (i < 1152 * 10) bij[i] = 0.f;
}

// enc_w1 [512][160] -> w1t [160][512]
__global__ void k_w1t(const float* __restrict__ w1, float* __restrict__ w1t) {
    int i = blockIdx.x * 256 + threadIdx.x;  // 81920
    int j = i / 160, k = i % 160;
    w1t[k * 512 + j] = w1[i];
}

// conv_w [256][81] -> cwt [81][256]
__global__ void k_cwt(const float* __restrict__ cw, float* __restrict__ cwt) {
    cwt[blockIdx.x * 256 + threadIdx.x] = cw[threadIdx.x * 81 + blockIdx.x];
}

// pc_w f32 [oc][ic][81] -> W2t bf16 [oc][k] with k = t*256 + ic  (t = kh*9+kw)
__global__ void k_w2t(const float* __restrict__ pcw, bf16_t* __restrict__ w2t) {
    __shared__ bf16_t tmp[20736];
    int oc = blockIdx.x;
    const float* src = pcw + (size_t)oc * 20736;
    for (int q = threadIdx.x; q < 20736; q += 256) {
        int ic = q / 81, t = q % 81;
        tmp[t * 256 + ic] = (bf16_t)src[q];
    }
    __syncthreads();
    bf16_t* dst = w2t + (size_t)oc * 20736;
    for (int q = threadIdx.x; q < 20736; q += 256) dst[q] = tmp[q];
}

// ---------------- conv1 + relu -> x_t NHWC bf16 [b][20][20][256] ----------------
__global__ __launch_bounds__(320) void k_conv1(const float* __restrict__ data,
                                               const float* __restrict__ cwt,
                                               const float* __restrict__ cb,
                                               bf16_t* __restrict__ xt) {
    __shared__ float img[784];
    int b = blockIdx.x >> 2, ocb = blockIdx.x & 3;
    int tid = threadIdx.x;
    for (int i = tid; i < 784; i += 320) img[i] = data[b * 784 + i];
    __syncthreads();
    int ocg = tid & 15, oh = tid >> 4;
    int oc4 = ocb * 64 + ocg * 4;
    f32x4 bias = *(const f32x4*)&cb[oc4];
    f32x4 acc[20];
#pragma unroll
    for (int ow = 0; ow < 20; ++ow) acc[ow] = (f32x4){0.f, 0.f, 0.f, 0.f};
    for (int kh = 0; kh < 9; ++kh) {
        float row[28];
#pragma unroll
        for (int q = 0; q < 7; ++q) {
            f32x4 t = *(const f32x4*)&img[(oh + kh) * 28 + q * 4];
            row[q * 4 + 0] = t.x; row[q * 4 + 1] = t.y;
            row[q * 4 + 2] = t.z; row[q * 4 + 3] = t.w;
        }
#pragma unroll
        for (int kw = 0; kw < 9; ++kw) {
            f32x4 w = *(const f32x4*)&cwt[(kh * 9 + kw) * 256 + oc4];
#pragma unroll
            for (int ow = 0; ow < 20; ++ow) acc[ow] += w * row[ow + kw];
        }
    }
    size_t base = ((size_t)(b * 20 + oh) * 20) * 256 + oc4;
#pragma unroll
    for (int ow = 0; ow < 20; ++ow) {
        f32x4 r = acc[ow] + bias;
        bf16x4 vv;
        vv[0] = (bf16_t)fmaxf(r.x, 0.f);
        vv[1] = (bf16_t)fmaxf(r.y, 0.f);
        vv[2] = (bf16_t)fmaxf(r.z, 0.f);
        vv[3] = (bf16_t)fmaxf(r.w, 0.f);
        *(bf16x4*)&xt[base + (size_t)ow * 256] = vv;
    }
}

// ---------------- PrimaryCaps implicit GEMM, counted-vmcnt pipelined (T3+T4+T5) ----------------
// C[M=18432][N=256] = A x B ; m=b*36+pos, n=oc, k=(kh*9+kw)*256+ic
// grid 432 = 72 m-tiles(256) x 2 n-tiles(128) x 3 k-splits ; BK=64, 108 K-tiles/block.
// 3-deep LDS pipeline: stage tile t+2 while computing t; 6 gload_lds per tile;
// steady-state wait = vmcnt(6) (tile t+2's loads stay in flight) + barrier.
__global__ __launch_bounds__(512) void k_pcgemm(const bf16_t* __restrict__ xt,
                                                const bf16_t* __restrict__ w2t,
                                                bf16_t* __restrict__ parts) {
    __shared__ __align__(16) bf16_t As[3 * 256 * 64];  // 96 KiB
    __shared__ __align__(16) bf16_t Bs[3 * 128 * 64];  // 48 KiB
    int bid = blockIdx.x;
    int mt = bid % 72;
    int nt = (bid / 72) & 1;
    int ks = bid / 144;  // 0..2
    int m0 = mt * 256, n0 = nt * 128;
    int tid = threadIdx.x, lane = tid & 63, wave = tid >> 6;
    int wm = wave >> 2, wn = wave & 3;

    int csrc = (tid & 7) ^ ((tid >> 3) & 7);  // swizzled source chunk
    int arow[4];
#pragma unroll
    for (int p = 0; p < 4; ++p) {
        int m = m0 + p * 64 + (tid >> 3);
        int bb = m / 36, pos = m % 36;
        int oh = pos / 6, ow = pos % 6;
        arow[p] = ((bb * 20 + oh * 2) * 20 + ow * 2) * 256;
    }
    const bf16_t* bbase0 = w2t + (size_t)(n0 + 0 * 64 + (tid >> 3)) * 20736 + csrc * 8;
    const bf16_t* bbase1 = w2t + (size_t)(n0 + 1 * 64 + (tid >> 3)) * 20736 + csrc * 8;

    // staging counters (tile being staged)
    int s0 = ks * 108;
    int sicb = s0 & 3;
    int skhkw = s0 >> 2;
    int skh = skhkw / 9, skw = skhkw - (skhkw / 9) * 9;
    int stile = s0;

#define STAGE_P0(BUF) do {                                                        \
        int aoff_ = (skh * 20 + skw) * 256 + sicb * 64 + csrc * 8;                \
        gload_lds16(xt + arow[0] + aoff_, &As[(BUF) * 16384 + 0 * 4096 + tid * 8]); \
        gload_lds16(xt + arow[1] + aoff_, &As[(BUF) * 16384 + 1 * 4096 + tid * 8]); \
        gload_lds16(xt + arow[2] + aoff_, &As[(BUF) * 16384 + 2 * 4096 + tid * 8]); \
    } while (0)
#define STAGE_P1(BUF) do {                                                        \
        int aoff_ = (skh * 20 + skw) * 256 + sicb * 64 + csrc * 8;                \
        gload_lds16(xt + arow[3] + aoff_, &As[(BUF) * 16384 + 3 * 4096 + tid * 8]); \
        gload_lds16(bbase0 + (size_t)stile * 64, &Bs[(BUF) * 8192 + 0 * 4096 + tid * 8]); \
        gload_lds16(bbase1 + (size_t)stile * 64, &Bs[(BUF) * 8192 + 1 * 4096 + tid * 8]); \
        ++stile;                                                                  \
        if (++sicb == 4) { sicb = 0; if (++skw == 9) { skw = 0; ++skh; } }        \
    } while (0)

    // prologue: stage tiles 0 and 1
    STAGE_P0(0); STAGE_P1(0);
    STAGE_P0(1); STAGE_P1(1);

    f32x4 acc[8][2];
#pragma unroll
    for (int i = 0; i < 8; ++i)
#pragma unroll
        for (int j = 0; j < 2; ++j) acc[i][j] = (f32x4){0.f, 0.f, 0.f, 0.f};

    int ard = (wm * 128 + (lane & 15)) * 64;   // A read base (row part)
    int brd = (wn * 32 + (lane & 15)) * 64;    // B read base
    int rx = lane & 7;
    int ch0 = ((0 * 4 + (lane >> 4)) ^ rx) * 8;  // kk=0 swizzled chunk
    int ch1 = ((1 * 4 + (lane >> 4)) ^ rx) * 8;  // kk=1

    for (int t = 0; t < 108; ++t) {
        int bufA = (t % 3) * 16384;
        int bufB = (t % 3) * 8192;
        int bufS = (t + 2) % 3;
        if (t < 107) { asm volatile("s_waitcnt vmcnt(6)" ::: "memory"); }
        else         { asm volatile("s_waitcnt vmcnt(0)" ::: "memory"); }
        HW_BARRIER();

        // ---- phase 1: A m-frags 0..3, B frags; MFMA quadrant m0 ----
        bf16x8 af[4][2], bf[2][2];
#pragma unroll
        for (int i = 0; i < 4; ++i) {
            af[i][0] = *(const bf16x8*)&As[bufA + ard + i * 1024 + ch0];
            af[i][1] = *(const bf16x8*)&As[bufA + ard + i * 1024 + ch1];
        }
#pragma unroll
        for (int j = 0; j < 2; ++j) {
            bf[j][0] = *(const bf16x8*)&Bs[bufB + brd + j * 1024 + ch0];
            bf[j][1] = *(const bf16x8*)&Bs[bufB + brd + j * 1024 + ch1];
        }
        if (t <= 105) STAGE_P0(bufS);
        HW_BARRIER();
        __builtin_amdgcn_s_setprio(1);
#pragma unroll
        for (int i = 0; i < 4; ++i)
#pragma unroll
            for (int j = 0; j < 2; ++j) {
                acc[i][j] = __builtin_amdgcn_mfma_f32_16x16x32_bf16(af[i][0], bf[j][0], acc[i][j], 0, 0, 0);
                acc[i][j] = __builtin_amdgcn_mfma_f32_16x16x32_bf16(af[i][1], bf[j][1], acc[i][j], 0, 0, 0);
            }
        __builtin_amdgcn_s_setprio(0);

        // ---- phase 2: A m-frags 4..7 (B reused); MFMA quadrant m1 ----
        bf16x8 af2[4][2];
#pragma unroll
        for (int i = 0; i < 4; ++i) {
            af2[i][0] = *(const bf16x8*)&As[bufA + ard + (4 + i) * 1024 + ch0];
            af2[i][1] = *(const bf16x8*)&As[bufA + ard + (4 + i) * 1024 + ch1];
        }
        if (t <= 105) STAGE_P1(bufS);
        HW_BARRIER();
        __builtin_amdgcn_s_setprio(1);
#pragma unroll
        for (int i = 0; i < 4; ++i)
#pragma unroll
            for (int j = 0; j < 2; ++j) {
                acc[4 + i][j] = __builtin_amdgcn_mfma_f32_16x16x32_bf16(af2[i][0], bf[j][0], acc[4 + i][j], 0, 0, 0);
                acc[4 + i][j] = __builtin_amdgcn_mfma_f32_16x16x32_bf16(af2[i][1], bf[j][1], acc[4 + i][j], 0, 0, 0);
            }
        __builtin_amdgcn_s_setprio(0);
    }
#undef STAGE_P0
#undef STAGE_P1

    bf16_t* out = parts + (size_t)ks * 4718592;
    int mbase = m0 + wm * 128 + (lane >> 4) * 4;
    int nbase = n0 + wn * 32 + (lane & 15);
#pragma unroll
    for (int i = 0; i < 8; ++i)
#pragma unroll
        for (int j = 0; j < 2; ++j)
#pragma unroll
            for (int jj = 0; jj < 4; ++jj)
                out[(size_t)(mbase + i * 16 + jj) * 256 + nbase + j * 16] = (bf16_t)acc[i][j][jj];
}

// ---------------- squash -> u bf16 [b][flat], flat = oc*36+pos ----------------
__global__ __launch_bounds__(256) void k_squash(const bf16_t* __restrict__ parts,
                                                const float* __restrict__ pcb,
                                                bf16_t* __restrict__ ub) {
    __shared__ float s[9216];
    int b = blockIdx.x, tid = threadIdx.x;
    for (int i = tid; i < 9216; i += 256) {
        float a = pcb[i & 255];
#pragma unroll
        for (int p = 0; p < 3; ++p) a += (float)parts[(size_t)p * 4718592 + (size_t)b * 9216 + i];
        s[i] = a;
    }
    __syncthreads();
    for (int r = tid; r < 1152; r += 256) {
        int flat0 = r * 8;
        float val[8], sn = 0.f;
#pragma unroll
        for (int e = 0; e < 8; ++e) {
            int f = flat0 + e;
            float x = s[(f % 36) * 256 + f / 36];
            val[e] = x;
            sn += x * x;
        }
        float scale = sn / ((1.f + sn) * sqrtf(sn));
        bf16x8 vv;
#pragma unroll
        for (int e = 0; e < 8; ++e) vv[e] = (bf16_t)(val[e] * scale);
        *(bf16x8*)&ub[(size_t)b * 9216 + flat0] = vv;
    }
}

// ---------------- u bf16 [512][9216] -> uT bf16 [9216][512] ----------------
__global__ __launch_bounds__(256) void k_uT(const bf16_t* __restrict__ ub, bf16_t* __restrict__ uT) {
    __shared__ bf16_t t[64 * 66];
    int kt = blockIdx.x % 144, bt = blockIdx.x / 144;
    int k0 = kt * 64, b0 = bt * 64;
    int tid = threadIdx.x;
    int c8 = tid & 7;
#pragma unroll
    for (int p = 0; p < 2; ++p) {
        int r = p * 32 + (tid >> 3);  // b-local
        bf16x8 vv = *(const bf16x8*)&ub[(size_t)(b0 + r) * 9216 + k0 + c8 * 8];
        uint32_t u4[4];
        *(bf16x8*)u4 = vv;
#pragma unroll
        for (int j2 = 0; j2 < 4; ++j2)
            *(uint32_t*)&t[r * 66 + c8 * 8 + j2 * 2] = u4[j2];
    }
    __syncthreads();
#pragma unroll
    for (int p = 0; p < 2; ++p) {
        int kp = p * 32 + (tid >> 3);  // k-local
        bf16x8 vv;
#pragma unroll
        for (int j = 0; j < 8; ++j) vv[j] = t[(c8 * 8 + j) * 66 + kp];
        *(bf16x8*)&uT[(size_t)(k0 + kp) * 512 + b0 + c8 * 8] = vv;
    }
}

// ---------------- v f32 [512][160] -> vT bf16 [160][512] ----------------
__global__ __launch_bounds__(256) void k_vt(const float* __restrict__ v, bf16_t* __restrict__ vT) {
    __shared__ float tf[32 * 65];
    int ct = blockIdx.x % 5, bt = blockIdx.x / 5;
    int c0 = ct * 32, b0 = bt * 64;
    int tid = threadIdx.x;
    for (int i = tid; i < 2048; i += 256) {
        int r = i >> 5, c = i & 31;
        tf[c * 65 + r] = v[(size_t)(b0 + r) * 160 + c0 + c];
    }
    __syncthreads();
    for (int i = tid; i < 2048; i += 256) {
        int c = i >> 6, r = i & 63;
        vT[(size_t)(c0 + c) * 512 + b0 + r] = (bf16_t)tf[c * 65 + r];
    }
}

// ---------------- shared NT MFMA kernel: C[M][160] = A[M][K] x B[160][K]^T ----------------
__global__ __launch_bounds__(256) void k_rgemm(const bf16_t* __restrict__ A,
                                               const bf16_t* __restrict__ B,
                                               float* __restrict__ Cp,
                                               int Kfull, int steps, int mtiles) {
    __shared__ __align__(16) bf16_t As[64 * 64];
    __shared__ __align__(16) bf16_t Bs[160 * 64];
    int bid = blockIdx.x;
    int mt = bid % mtiles, ks = bid / mtiles;
    int m0 = mt * 64;
    int k0 = ks * steps * 64;
    int tid = threadIdx.x, lane = tid & 63, wave = tid >> 6;
    int srow = tid >> 3;                       // 0..31
    int csrc = (tid & 7) ^ (srow & 7);
    const bf16_t* asrc[2];
    const bf16_t* bsrc[5];
#pragma unroll
    for (int p = 0; p < 2; ++p)
        asrc[p] = A + (size_t)(m0 + p * 32 + srow) * Kfull + k0 + csrc * 8;
#pragma unroll
    for (int p = 0; p < 5; ++p)
        bsrc[p] = B + (size_t)(p * 32 + srow) * Kfull + k0 + csrc * 8;

    f32x4 acc[2][5];
#pragma unroll
    for (int mi = 0; mi < 2; ++mi)
#pragma unroll
        for (int nj = 0; nj < 5; ++nj) acc[mi][nj] = (f32x4){0.f, 0.f, 0.f, 0.f};

    int mr = (wave >> 1) * 32 + (lane & 15);
    int nr = (wave & 1) * 80 + (lane & 15);
    int rx = lane & 7;

    for (int it = 0; it < steps; ++it) {
#pragma unroll
        for (int p = 0; p < 2; ++p) gload_lds16(asrc[p] + it * 64, As + p * 2048 + tid * 8);
#pragma unroll
        for (int p = 0; p < 5; ++p) gload_lds16(bsrc[p] + it * 64, Bs + p * 2048 + tid * 8);
        __syncthreads();
#pragma unroll
        for (int kk = 0; kk < 2; ++kk) {
            int ch = ((kk * 4 + (lane >> 4)) ^ rx) * 8;
            bf16x8 af[2], bfr[5];
#pragma unroll
            for (int i = 0; i < 2; ++i) af[i] = *(const bf16x8*)&As[(mr + i * 16) * 64 + ch];
#pragma unroll
            for (int j = 0; j < 5; ++j) bfr[j] = *(const bf16x8*)&Bs[(nr + j * 16) * 64 + ch];
#pragma unroll
            for (int mi = 0; mi < 2; ++mi)
#pragma unroll
                for (int nj = 0; nj < 5; ++nj)
                    acc[mi][nj] = __builtin_amdgcn_mfma_f32_16x16x32_bf16(af[mi], bfr[nj], acc[mi][nj], 0, 0, 0);
        }
        __syncthreads();
    }

    float* out = Cp + (size_t)ks * ((size_t)mtiles * 64 * 160);
    int mbase = m0 + (wave >> 1) * 32 + (lane >> 4) * 4;
    int nbase = (wave & 1) * 80 + (lane & 15);
#pragma unroll
    for (int mi = 0; mi < 2; ++mi)
#pragma unroll
        for (int nj = 0; nj < 5; ++nj)
#pragma unroll
            for (int j = 0; j < 4; ++j)
                out[(size_t)(mbase + mi * 16 + j) * 160 + nbase + nj * 16] = acc[mi][nj][j];
}

// ---------------- routing glue ----------------
__global__ void k_softmax(const float* __restrict__ bij, float* __restrict__ cij) {
    __shared__ float red[256];
    int c = blockIdx.x, tid = threadIdx.x;
    float mx = -1e30f;
    for (int r = tid; r < 1152; r += 256) mx = fmaxf(mx, bij[r * 10 + c]);
    red[tid] = mx; __syncthreads();
    for (int s = 128; s > 0; s >>= 1) { if (tid < s) red[tid] = fmaxf(red[tid], red[tid + s]); __syncthreads(); }
    float MX = red[0]; __syncthreads();
    float sm = 0.f;
    for (int r = tid; r < 1152; r += 256) sm += expf(bij[r * 10 + c] - MX);
    red[tid] = sm; __syncthreads();
    for (int s = 128; s > 0; s >>= 1) { if (tid < s) red[tid] += red[tid + s]; __syncthreads(); }
    float inv = 1.f / red[0];
    for (int r = tid; r < 1152; r += 256) cij[r * 10 + c] = expf(bij[r * 10 + c] - MX) * inv;
}

// cw2T bf16 [co=160][k=9216]: cw2T[co][k] = c[r][c]*W[r][c][o][i], k=8r+i, co=16c+o
__global__ void k_fold(const float* __restrict__ cij, const float* __restrict__ W,
                       bf16_t* __restrict__ cw2T) {
    int idx = blockIdx.x * 256 + threadIdx.x;  // 1474560
    int co = idx / 9216, k = idx % 9216;
    int r = k >> 3, i = k & 7;
    int c = co >> 4, o = co & 15;
    cw2T[idx] = (bf16_t)(cij[r * 10 + c] * W[((size_t)(r * 10 + c) * 16 + o) * 8 + i]);
}

// v[b][co] = squash1(sum_{ks<36} sp)
__global__ void k_vcomp(const float* __restrict__ sp, float* __restrict__ v) {
    int idx = blockIdx.x * 256 + threadIdx.x;  // 81920
    float s = 0.f;
#pragma unroll
    for (int p = 0; p < 36; ++p) s += sp[(size_t)p * 81920 + idx];
    v[idx] = s * fabsf(s) / (1.f + s * s);
}

// b_ij[r][c] += (1/512) sum_{i,o} W[r][c][o][i] * (Gp0+Gp1)[8r+i][16c+o]
__global__ void k_amean(const float* __restrict__ W, const float* __restrict__ Gp,
                        float* __restrict__ bij) {
    int idx = blockIdx.x * 256 + threadIdx.x;  // 11520
    if (idx >= 11520) return;
    int r = idx / 10, c = idx % 10;
    float s = 0.f;
    for (int o = 0; o < 16; ++o)
#pragma unroll
        for (int i = 0; i < 8; ++i) {
            size_t gi = (size_t)(r * 8 + i) * 160 + c * 16 + o;
            s += W[((size_t)(r * 10 + c) * 16 + o) * 8 + i] * (Gp[gi] + Gp[1474560 + gi]);
        }
    bij[idx] += s * (1.0f / 512.0f);
}

// ---------------- encoder ----------------
__global__ void k_enc1(const float* __restrict__ v, const float* __restrict__ w1t,
                       const float* __restrict__ b1, float* __restrict__ h) {
    __shared__ float fl[160];
    int b = blockIdx.x, tid = threadIdx.x;
    if (tid < 160) fl[tid] = v[b * 160 + tid];
    __syncthreads();
    for (int j = tid; j < 512; j += 256) {
        float s = b1[j];
#pragma unroll 8
        for (int k = 0; k < 160; ++k) s += fl[k] * w1t[k * 512 + j];
        h[(size_t)b * 512 + j] = fmaxf(s, 0.f);
    }
}

__global__ void k_enc2(const float* __restrict__ h, const float* __restrict__ w2,
                       const float* __restrict__ b2, float* __restrict__ out) {
    int idx = blockIdx.x * 256 + threadIdx.x;  // 4608
    int b = idx / 9, jj = idx % 9;
    float s = b2[jj];
    for (int k = 0; k < 512; ++k) s += h[(size_t)b * 512 + k] * w2[jj * 512 + k];
    out[idx] = 1.f / (1.f + expf(-s));
}

// ---------------- launch ----------------
extern "C" void kernel_launch(void* const* d_in, const int* in_sizes, int n_in,
                              void* d_out, int out_size, void* d_ws, size_t ws_size,
                              hipStream_t stream) {
    const float* data   = (const float*)d_in[0];
    const float* conv_w = (const float*)d_in[1];
    const float* conv_b = (const float*)d_in[2];
    const float* pc_w   = (const float*)d_in[3];
    const float* pc_b   = (const float*)d_in[4];
    const float* W      = (const float*)d_in[5];
    const float* enc_w1 = (const float*)d_in[6];
    const float* enc_b1 = (const float*)d_in[7];
    const float* enc_w2 = (const float*)d_in[8];
    const float* enc_b2 = (const float*)d_in[9];

    char* ws = (char*)d_ws;
    bf16_t* xt    = (bf16_t*)(ws + 0);            // 104,857,600
    bf16_t* w2t   = (bf16_t*)(ws + 104857600);    //  10,616,832 -> 115,474,432
    bf16_t* parts = (bf16_t*)(ws + 115474432);    //  28,311,552 (3 x 4,718,592 elems bf16)
    // overlay inside parts region (all used only after k_squash consumed parts):
    bf16_t* uT    = (bf16_t*)(ws + 115474432);    //   9,437,184
    bf16_t* cw2T  = (bf16_t*)(ws + 124911616);    //   2,949,120
    float*  sp    = (float*)(ws + 127860736);     //  11,796,480
    float*  Gp    = (float*)(ws + 139657216);     //  11,796,480 -> 151,453,696
    bf16_t* ub    = (bf16_t*)(ws + 153223168);    //   9,437,184 -> 162,660,352
    float*  v     = (float*)(ws + 162660352);     //     327,680
    bf16_t* vT    = (bf16_t*)(ws + 162988032);    //     163,840
    float*  h     = (float*)(ws + 163151872);     //   1,048,576
    float*  w1t   = (float*)(ws + 164200448);     //     327,680
    float*  bij   = (float*)(ws + 164528128);     //      46,080
    float*  cij   = (float*)(ws + 164574208);     //      46,080
    float*  cwt   = (float*)(ws + 164620288);     //      82,944  -> 164,703,232 total
    float*  outp  = (float*)d_out;

    hipLaunchKernelGGL(k_init_bij, dim3(45), dim3(256), 0, stream, bij);
    hipLaunchKernelGGL(k_w1t, dim3(320), dim3(256), 0, stream, enc_w1, w1t);
    hipLaunchKernelGGL(k_cwt, dim3(81), dim3(256), 0, stream, conv_w, cwt);
    hipLaunchKernelGGL(k_w2t, dim3(256), dim3(256), 0, stream, pc_w, w2t);
    hipLaunchKernelGGL(k_conv1, dim3(2048), dim3(320), 0, stream, data, cwt, conv_b, xt);
    hipLaunchKernelGGL(k_pcgemm, dim3(432), dim3(512), 0, stream, xt, w2t, parts);
    hipLaunchKernelGGL(k_squash, dim3(512), dim3(256), 0, stream, parts, pc_b, ub);
    hipLaunchKernelGGL(k_uT, dim3(1152), dim3(256), 0, stream, ub, uT);
    for (int it = 0; it < 3; ++it) {
        hipLaunchKernelGGL(k_softmax, dim3(10), dim3(256), 0, stream, bij, cij);
        hipLaunchKernelGGL(k_fold, dim3(5760), dim3(256), 0, stream, cij, W, cw2T);
        // s partials: A=ub [512][9216], B=cw2T [160][9216]; mtiles=8, ksplit=36, steps=4
        hipLaunchKernelGGL(k_rgemm, dim3(288), dim3(256), 0, stream, ub, cw2T, sp, 9216, 4, 8);
        hipLaunchKernelGGL(k_vcomp, dim3(320), dim3(256), 0, stream, sp, v);
        if (it < 2) {
            hipLaunchKernelGGL(k_vt, dim3(40), dim3(256), 0, stream, v, vT);
            // G partials: A=uT [9216][512], B=vT [160][512]; mtiles=144, ksplit=2, steps=4
            hipLaunchKernelGGL(k_rgemm, dim3(288), dim3(256), 0, stream, uT, vT, Gp, 512, 4, 144);
            hipLaunchKernelGGL(k_amean, dim3(45), dim3(256), 0, stream, W, Gp, bij);
        }
    }
    hipLaunchKernelGGL(k_enc1, dim3(512), dim3(256), 0, stream, v, w1t, enc_b1, h);
    hipLaunchKernelGGL(k_enc2, dim3(18), dim3(256), 0, stream, h, enc_w2, enc_b2, outp);
}

// Round 5
// 538.131 us; speedup vs baseline: 2.6558x; 1.0167x over previous
//
#include <hip/hip_runtime.h>
#include <hip/hip_bf16.h>
#include <stdint.h>

// CapsNet forward. B=512, conv1 1->256 9x9 s1 (28->20), pc 256->256 9x9 s2 (20->6),
// routes R=1152, caps C=10, I=8, O=16, encoder 160->512->9.

typedef __bf16 bf16_t;
typedef __bf16 bf16x4 __attribute__((ext_vector_type(4)));
typedef __bf16 bf16x8 __attribute__((ext_vector_type(8)));
typedef float f32x4 __attribute__((ext_vector_type(4)));

__device__ __forceinline__ void gload_lds16(const void* g, void* l) {
    __builtin_amdgcn_global_load_lds((const __attribute__((address_space(1))) void*)g,
                                     (__attribute__((address_space(3))) void*)l, 16, 0, 0);
}

#define MEMBAR() asm volatile("" ::: "memory")
#define HW_BARRIER() do { MEMBAR(); __builtin_amdgcn_s_barrier(); MEMBAR(); } while (0)

// ---------------- prep kernels ----------------
__global__ void k_init_bij(float* bij) {
    int i = blockIdx.x * 256 + threadIdx.x;
    if (i < 1152 * 10) bij[i] = 0.f;
}

// enc_w1 [512][160] -> w1t [160][512]
__global__ void k_w1t(const float* __restrict__ w1, float* __restrict__ w1t) {
    int i = blockIdx.x * 256 + threadIdx.x;  // 81920
    int j = i / 160, k = i % 160;
    w1t[k * 512 + j] = w1[i];
}

// conv_w [256][81] -> cwt [81][256]
__global__ void k_cwt(const float* __restrict__ cw, float* __restrict__ cwt) {
    cwt[blockIdx.x * 256 + threadIdx.x] = cw[threadIdx.x * 81 + blockIdx.x];
}

// pc_w f32 [oc][ic][81] -> W2t bf16 [oc][k] with k = t*256 + ic  (t = kh*9+kw)
__global__ void k_w2t(const float* __restrict__ pcw, bf16_t* __restrict__ w2t) {
    __shared__ bf16_t tmp[20736];
    int oc = blockIdx.x;
    const float* src = pcw + (size_t)oc * 20736;
    for (int q = threadIdx.x; q < 20736; q += 256) {
        int ic = q / 81, t = q % 81;
        tmp[t * 256 + ic] = (bf16_t)src[q];
    }
    __syncthreads();
    bf16_t* dst = w2t + (size_t)oc * 20736;
    for (int q = threadIdx.x; q < 20736; q += 256) dst[q] = tmp[q];
}

// ---------------- conv1 + relu -> x_t NHWC bf16 [b][20][20][256] ----------------
__global__ __launch_bounds__(320) void k_conv1(const float* __restrict__ data,
                                               const float* __restrict__ cwt,
                                               const float* __restrict__ cb,
                                               bf16_t* __restrict__ xt) {
    __shared__ float img[784];
    int b = blockIdx.x >> 2, ocb = blockIdx.x & 3;
    int tid = threadIdx.x;
    for (int i = tid; i < 784; i += 320) img[i] = data[b * 784 + i];
    __syncthreads();
    int ocg = tid & 15, oh = tid >> 4;
    int oc4 = ocb * 64 + ocg * 4;
    f32x4 bias = *(const f32x4*)&cb[oc4];
    f32x4 acc[20];
#pragma unroll
    for (int ow = 0; ow < 20; ++ow) acc[ow] = (f32x4){0.f, 0.f, 0.f, 0.f};
    for (int kh = 0; kh < 9; ++kh) {
        float row[28];
#pragma unroll
        for (int q = 0; q < 7; ++q) {
            f32x4 t = *(const f32x4*)&img[(oh + kh) * 28 + q * 4];
            row[q * 4 + 0] = t.x; row[q * 4 + 1] = t.y;
            row[q * 4 + 2] = t.z; row[q * 4 + 3] = t.w;
        }
#pragma unroll
        for (int kw = 0; kw < 9; ++kw) {
            f32x4 w = *(const f32x4*)&cwt[(kh * 9 + kw) * 256 + oc4];
#pragma unroll
            for (int ow = 0; ow < 20; ++ow) acc[ow] += w * row[ow + kw];
        }
    }
    size_t base = ((size_t)(b * 20 + oh) * 20) * 256 + oc4;
#pragma unroll
    for (int ow = 0; ow < 20; ++ow) {
        f32x4 r = acc[ow] + bias;
        bf16x4 vv;
        vv[0] = (bf16_t)fmaxf(r.x, 0.f);
        vv[1] = (bf16_t)fmaxf(r.y, 0.f);
        vv[2] = (bf16_t)fmaxf(r.z, 0.f);
        vv[3] = (bf16_t)fmaxf(r.w, 0.f);
        *(bf16x4*)&xt[base + (size_t)ow * 256] = vv;
    }
}

// ---------------- PrimaryCaps implicit GEMM, double-buffered prefetch (T3 min 2-phase) ----------------
// C[M=18432][N=256] = A x B ; m=b*36+pos, n=oc, k=(kh*9+kw)*256+ic
// grid 1152 = 144 m-tiles x 2 n-tiles x 4 k-splits ; tile 128x128, BK=64, 81 tiles.
// Per tile: issue next tile's 6 gload_lds FIRST, then ds_read+MFMA on current,
// then one vmcnt(0)+barrier (loads landed during MFMA).
__global__ __launch_bounds__(256) void k_pcgemm(const bf16_t* __restrict__ xt,
                                                const bf16_t* __restrict__ w2t,
                                                bf16_t* __restrict__ parts) {
    __shared__ __align__(16) bf16_t As[2 * 128 * 64];
    __shared__ __align__(16) bf16_t Bs[2 * 128 * 64];
    int bid = blockIdx.x;
    int mt = bid % 144;
    int nt = (bid / 144) & 1;
    int ks = bid / 288;  // 0..3
    int m0 = mt * 128, n0 = nt * 128;
    int tid = threadIdx.x, lane = tid & 63, wave = tid >> 6;

    int csrc = (tid & 7) ^ ((tid >> 3) & 7);  // swizzled source chunk
    int arow[4];
#pragma unroll
    for (int p = 0; p < 4; ++p) {
        int m = m0 + p * 32 + (tid >> 3);
        int bb = m / 36, pos = m % 36;
        int oh = pos / 6, ow = pos % 6;
        arow[p] = ((bb * 20 + oh * 2) * 20 + ow * 2) * 256;
    }
    const bf16_t* bbase = w2t + (size_t)(n0 + (tid >> 3)) * 20736 + csrc * 8;

    f32x4 acc[4][4];
#pragma unroll
    for (int mi = 0; mi < 4; ++mi)
#pragma unroll
        for (int ni = 0; ni < 4; ++ni) acc[mi][ni] = (f32x4){0.f, 0.f, 0.f, 0.f};

    // staging state
    int s0 = ks * 81;
    int sicb = s0 & 3;
    int st0 = s0 >> 2;
    int skh = st0 / 9, skw = st0 - (st0 / 9) * 9;
    int stile = s0;

#define PSTAGE(BUF) do {                                                            \
        int aoff_ = (skh * 20 + skw) * 256 + sicb * 64 + csrc * 8;                  \
        const bf16_t* bsrc_ = bbase + (size_t)stile * 64;                           \
        gload_lds16(xt + arow[0] + aoff_, &As[(BUF) * 8192 + 0 * 2048 + tid * 8]);  \
        gload_lds16(bsrc_ + (size_t)0 * 32 * 20736, &Bs[(BUF) * 8192 + 0 * 2048 + tid * 8]); \
        gload_lds16(xt + arow[1] + aoff_, &As[(BUF) * 8192 + 1 * 2048 + tid * 8]);  \
        gload_lds16(bsrc_ + (size_t)1 * 32 * 20736, &Bs[(BUF) * 8192 + 1 * 2048 + tid * 8]); \
        gload_lds16(xt + arow[2] + aoff_, &As[(BUF) * 8192 + 2 * 2048 + tid * 8]);  \
        gload_lds16(bsrc_ + (size_t)2 * 32 * 20736, &Bs[(BUF) * 8192 + 2 * 2048 + tid * 8]); \
        gload_lds16(xt + arow[3] + aoff_, &As[(BUF) * 8192 + 3 * 2048 + tid * 8]);  \
        gload_lds16(bsrc_ + (size_t)3 * 32 * 20736, &Bs[(BUF) * 8192 + 3 * 2048 + tid * 8]); \
        ++stile;                                                                    \
        if (++sicb == 4) { sicb = 0; if (++skw == 9) { skw = 0; ++skh; } }          \
    } while (0)

    // prologue: stage tile 0 into buf 0
    PSTAGE(0);
    asm volatile("s_waitcnt vmcnt(0)" ::: "memory");
    HW_BARRIER();

    int mr = (wave >> 1) * 64 + (lane & 15);
    int nr = (wave & 1) * 64 + (lane & 15);
    int rx = lane & 7;

    for (int t = 0; t < 81; ++t) {
        int cur = (t & 1) * 8192;
        if (t < 80) PSTAGE((t + 1) & 1);  // prefetch next tile into other buffer
#pragma unroll
        for (int kk = 0; kk < 2; ++kk) {
            int ch = ((kk * 4 + (lane >> 4)) ^ rx) * 8;  // swizzled read chunk
            bf16x8 af[4], bfr[4];
#pragma unroll
            for (int i = 0; i < 4; ++i) af[i] = *(const bf16x8*)&As[cur + (mr + i * 16) * 64 + ch];
#pragma unroll
            for (int i = 0; i < 4; ++i) bfr[i] = *(const bf16x8*)&Bs[cur + (nr + i * 16) * 64 + ch];
#pragma unroll
            for (int mi = 0; mi < 4; ++mi)
#pragma unroll
                for (int ni = 0; ni < 4; ++ni)
                    acc[mi][ni] = __builtin_amdgcn_mfma_f32_16x16x32_bf16(af[mi], bfr[ni], acc[mi][ni], 0, 0, 0);
        }
        asm volatile("s_waitcnt vmcnt(0)" ::: "memory");
        HW_BARRIER();
    }
#undef PSTAGE

    bf16_t* out = parts + (size_t)ks * 4718592;
    int mbase = m0 + (wave >> 1) * 64 + (lane >> 4) * 4;
    int nbase = n0 + (wave & 1) * 64 + (lane & 15);
#pragma unroll
    for (int mi = 0; mi < 4; ++mi)
#pragma unroll
        for (int ni = 0; ni < 4; ++ni)
#pragma unroll
            for (int j = 0; j < 4; ++j)
                out[(size_t)(mbase + mi * 16 + j) * 256 + nbase + ni * 16] = (bf16_t)acc[mi][ni][j];
}

// ---------------- squash -> u bf16 [b][flat], flat = oc*36+pos ----------------
// LDS stride padded 256->257 to break column-read bank conflicts.
__global__ __launch_bounds__(256) void k_squash(const bf16_t* __restrict__ parts,
                                                const float* __restrict__ pcb,
                                                bf16_t* __restrict__ ub) {
    __shared__ float s[36 * 257];
    int b = blockIdx.x, tid = threadIdx.x;
    for (int i = tid; i < 9216; i += 256) {
        float a = pcb[i & 255];
#pragma unroll
        for (int p = 0; p < 4; ++p) a += (float)parts[(size_t)p * 4718592 + (size_t)b * 9216 + i];
        s[(i >> 8) * 257 + (i & 255)] = a;
    }
    __syncthreads();
    for (int r = tid; r < 1152; r += 256) {
        int flat0 = r * 8;
        float val[8], sn = 0.f;
#pragma unroll
        for (int e = 0; e < 8; ++e) {
            int f = flat0 + e;
            float x = s[(f % 36) * 257 + f / 36];
            val[e] = x;
            sn += x * x;
        }
        float scale = sn / ((1.f + sn) * sqrtf(sn));
        bf16x8 vv;
#pragma unroll
        for (int e = 0; e < 8; ++e) vv[e] = (bf16_t)(val[e] * scale);
        *(bf16x8*)&ub[(size_t)b * 9216 + flat0] = vv;
    }
}

// ---------------- u bf16 [512][9216] -> uT bf16 [9216][512] ----------------
__global__ __launch_bounds__(256) void k_uT(const bf16_t* __restrict__ ub, bf16_t* __restrict__ uT) {
    __shared__ bf16_t t[64 * 66];
    int kt = blockIdx.x % 144, bt = blockIdx.x / 144;
    int k0 = kt * 64, b0 = bt * 64;
    int tid = threadIdx.x;
    int c8 = tid & 7;
#pragma unroll
    for (int p = 0; p < 2; ++p) {
        int r = p * 32 + (tid >> 3);  // b-local
        bf16x8 vv = *(const bf16x8*)&ub[(size_t)(b0 + r) * 9216 + k0 + c8 * 8];
        uint32_t u4[4];
        *(bf16x8*)u4 = vv;
#pragma unroll
        for (int j2 = 0; j2 < 4; ++j2)
            *(uint32_t*)&t[r * 66 + c8 * 8 + j2 * 2] = u4[j2];
    }
    __syncthreads();
#pragma unroll
    for (int p = 0; p < 2; ++p) {
        int kp = p * 32 + (tid >> 3);  // k-local
        bf16x8 vv;
#pragma unroll
        for (int j = 0; j < 8; ++j) vv[j] = t[(c8 * 8 + j) * 66 + kp];
        *(bf16x8*)&uT[(size_t)(k0 + kp) * 512 + b0 + c8 * 8] = vv;
    }
}

// ---------------- fold + fused softmax ----------------
// cw2T bf16 [co=160][k=9216]: cw2T[co][k] = softmax_r(bij)[r][c]*W[r][c][o][i]
// grid 5760: each block has fixed co (9216/256=36 blocks per co); computes the
// column-c softmax denom itself (bij is tiny, L2-resident).
__global__ __launch_bounds__(256) void k_fold(const float* __restrict__ bij,
                                              const float* __restrict__ W,
                                              bf16_t* __restrict__ cw2T) {
    __shared__ float red[256];
    int idx0 = blockIdx.x * 256;
    int co = idx0 / 9216;
    int c = co >> 4, o = co & 15;
    int tid = threadIdx.x;
    float mx = -1e30f;
    for (int r = tid; r < 1152; r += 256) mx = fmaxf(mx, bij[r * 10 + c]);
    red[tid] = mx; __syncthreads();
    for (int s = 128; s > 0; s >>= 1) { if (tid < s) red[tid] = fmaxf(red[tid], red[tid + s]); __syncthreads(); }
    float mxv = red[0];
    __syncthreads();
    float sm = 0.f;
    for (int r = tid; r < 1152; r += 256) sm += expf(bij[r * 10 + c] - mxv);
    red[tid] = sm; __syncthreads();
    for (int s = 128; s > 0; s >>= 1) { if (tid < s) red[tid] += red[tid + s]; __syncthreads(); }
    float inv = 1.f / red[0];
    int k = (idx0 + tid) % 9216;
    int r = k >> 3, i = k & 7;
    float cij = expf(bij[r * 10 + c] - mxv) * inv;
    cw2T[idx0 + tid] = (bf16_t)(cij * W[((size_t)(r * 10 + c) * 16 + o) * 8 + i]);
}

// ---------------- shared NT MFMA kernel: C[M][160] = A[M][K] x B[160][K]^T ----------------
__global__ __launch_bounds__(256) void k_rgemm(const bf16_t* __restrict__ A,
                                               const bf16_t* __restrict__ B,
                                               float* __restrict__ Cp,
                                               int Kfull, int steps, int mtiles) {
    __shared__ __align__(16) bf16_t As[64 * 64];
    __shared__ __align__(16) bf16_t Bs[160 * 64];
    int bid = blockIdx.x;
    int mt = bid % mtiles, ks = bid / mtiles;
    int m0 = mt * 64;
    int k0 = ks * steps * 64;
    int tid = threadIdx.x, lane = tid & 63, wave = tid >> 6;
    int srow = tid >> 3;                       // 0..31
    int csrc = (tid & 7) ^ (srow & 7);
    const bf16_t* asrc[2];
    const bf16_t* bsrc[5];
#pragma unroll
    for (int p = 0; p < 2; ++p)
        asrc[p] = A + (size_t)(m0 + p * 32 + srow) * Kfull + k0 + csrc * 8;
#pragma unroll
    for (int p = 0; p < 5; ++p)
        bsrc[p] = B + (size_t)(p * 32 + srow) * Kfull + k0 + csrc * 8;

    f32x4 acc[2][5];
#pragma unroll
    for (int mi = 0; mi < 2; ++mi)
#pragma unroll
        for (int nj = 0; nj < 5; ++nj) acc[mi][nj] = (f32x4){0.f, 0.f, 0.f, 0.f};

    int mr = (wave >> 1) * 32 + (lane & 15);
    int nr = (wave & 1) * 80 + (lane & 15);
    int rx = lane & 7;

    for (int it = 0; it < steps; ++it) {
#pragma unroll
        for (int p = 0; p < 2; ++p) gload_lds16(asrc[p] + it * 64, As + p * 2048 + tid * 8);
#pragma unroll
        for (int p = 0; p < 5; ++p) gload_lds16(bsrc[p] + it * 64, Bs + p * 2048 + tid * 8);
        __syncthreads();
#pragma unroll
        for (int kk = 0; kk < 2; ++kk) {
            int ch = ((kk * 4 + (lane >> 4)) ^ rx) * 8;
            bf16x8 af[2], bfr[5];
#pragma unroll
            for (int i = 0; i < 2; ++i) af[i] = *(const bf16x8*)&As[(mr + i * 16) * 64 + ch];
#pragma unroll
            for (int j = 0; j < 5; ++j) bfr[j] = *(const bf16x8*)&Bs[(nr + j * 16) * 64 + ch];
#pragma unroll
            for (int mi = 0; mi < 2; ++mi)
#pragma unroll
                for (int nj = 0; nj < 5; ++nj)
                    acc[mi][nj] = __builtin_amdgcn_mfma_f32_16x16x32_bf16(af[mi], bfr[nj], acc[mi][nj], 0, 0, 0);
        }
        __syncthreads();
    }

    float* out = Cp + (size_t)ks * ((size_t)mtiles * 64 * 160);
    int mbase = m0 + (wave >> 1) * 32 + (lane >> 4) * 4;
    int nbase = (wave & 1) * 80 + (lane & 15);
#pragma unroll
    for (int mi = 0; mi < 2; ++mi)
#pragma unroll
        for (int nj = 0; nj < 5; ++nj)
#pragma unroll
            for (int j = 0; j < 4; ++j)
                out[(size_t)(mbase + mi * 16 + j) * 160 + nbase + nj * 16] = acc[mi][nj][j];
}

// ---------------- v + vT from s partials ----------------
__global__ void k_vcomp(const float* __restrict__ sp, float* __restrict__ v,
                        bf16_t* __restrict__ vT) {
    int idx = blockIdx.x * 256 + threadIdx.x;  // 81920
    float s = 0.f;
#pragma unroll
    for (int p = 0; p < 36; ++p) s += sp[(size_t)p * 81920 + idx];
    float val = s * fabsf(s) / (1.f + s * s);
    v[idx] = val;
    int b = idx / 160, co = idx % 160;
    vT[(size_t)co * 512 + b] = (bf16_t)val;
}

// ---------------- G-gemm + amean fused: bij[r][c] += (1/512) W : (uT vT^T) ----------------
// grid 144 (one per 64-k tile = 8 routes); K=512, steps=8, no k-split.
__global__ __launch_bounds__(256) void k_ggemm2(const bf16_t* __restrict__ uT,
                                                const bf16_t* __restrict__ vT,
                                                const float* __restrict__ W,
                                                float* __restrict__ bij) {
    __shared__ __align__(16) bf16_t As[64 * 64];
    __shared__ __align__(16) bf16_t Bs[160 * 64];
    __shared__ float Gl[64 * 161];
    int mt = blockIdx.x;
    int m0 = mt * 64;
    int tid = threadIdx.x, lane = tid & 63, wave = tid >> 6;
    int srow = tid >> 3;
    int csrc = (tid & 7) ^ (srow & 7);
    const bf16_t* asrc[2];
    const bf16_t* bsrc[5];
#pragma unroll
    for (int p = 0; p < 2; ++p)
        asrc[p] = uT + (size_t)(m0 + p * 32 + srow) * 512 + csrc * 8;
#pragma unroll
    for (int p = 0; p < 5; ++p)
        bsrc[p] = vT + (size_t)(p * 32 + srow) * 512 + csrc * 8;

    f32x4 acc[2][5];
#pragma unroll
    for (int mi = 0; mi < 2; ++mi)
#pragma unroll
        for (int nj = 0; nj < 5; ++nj) acc[mi][nj] = (f32x4){0.f, 0.f, 0.f, 0.f};

    int mr = (wave >> 1) * 32 + (lane & 15);
    int nr = (wave & 1) * 80 + (lane & 15);
    int rx = lane & 7;

    for (int it = 0; it < 8; ++it) {
#pragma unroll
        for (int p = 0; p < 2; ++p) gload_lds16(asrc[p] + it * 64, As + p * 2048 + tid * 8);
#pragma unroll
        for (int p = 0; p < 5; ++p) gload_lds16(bsrc[p] + it * 64, Bs + p * 2048 + tid * 8);
        __syncthreads();
#pragma unroll
        for (int kk = 0; kk < 2; ++kk) {
            int ch = ((kk * 4 + (lane >> 4)) ^ rx) * 8;
            bf16x8 af[2], bfr[5];
#pragma unroll
            for (int i = 0; i < 2; ++i) af[i] = *(const bf16x8*)&As[(mr + i * 16) * 64 + ch];
#pragma unroll
            for (int j = 0; j < 5; ++j) bfr[j] = *(const bf16x8*)&Bs[(nr + j * 16) * 64 + ch];
#pragma unroll
            for (int mi = 0; mi < 2; ++mi)
#pragma unroll
                for (int nj = 0; nj < 5; ++nj)
                    acc[mi][nj] = __builtin_amdgcn_mfma_f32_16x16x32_bf16(af[mi], bfr[nj], acc[mi][nj], 0, 0, 0);
        }
        __syncthreads();
    }

    // G tile (64 k-rows x 160 co) -> LDS, scaled by 1/512
    int mbl = (wave >> 1) * 32 + (lane >> 4) * 4;
    int nbase = (wave & 1) * 80 + (lane & 15);
#pragma unroll
    for (int mi = 0; mi < 2; ++mi)
#pragma unroll
        for (int nj = 0; nj < 5; ++nj)
#pragma unroll
            for (int j = 0; j < 4; ++j)
                Gl[(mbl + mi * 16 + j) * 161 + nbase + nj * 16] = acc[mi][nj][j] * (1.0f / 512.0f);
    __syncthreads();
    // bij update for routes r = mt*8 .. mt*8+7
    if (tid < 80) {
        int rl = tid / 10, c = tid % 10;
        int r = mt * 8 + rl;
        const float* wbase = W + (size_t)(r * 10 + c) * 128;
        float s = 0.f;
#pragma unroll
        for (int o = 0; o < 16; ++o)
#pragma unroll
            for (int i = 0; i < 8; ++i)
                s += wbase[o * 8 + i] * Gl[(rl * 8 + i) * 161 + c * 16 + o];
        bij[r * 10 + c] += s;
    }
}

// ---------------- encoder (enc1+enc2 fused) ----------------
__global__ __launch_bounds__(256) void k_enc(const float* __restrict__ v,
                                             const float* __restrict__ w1t,
                                             const float* __restrict__ b1,
                                             const float* __restrict__ w2,
                                             const float* __restrict__ b2,
                                             float* __restrict__ out) {
    __shared__ float fl[160];
    __shared__ float h[512];
    int b = blockIdx.x, tid = threadIdx.x;
    if (tid < 160) fl[tid] = v[b * 160 + tid];
    __syncthreads();
    for (int j = tid; j < 512; j += 256) {
        float s = b1[j];
#pragma unroll 8
        for (int k = 0; k < 160; ++k) s += fl[k] * w1t[k * 512 + j];
        h[j] = fmaxf(s, 0.f);
    }
    __syncthreads();
    int wave = tid >> 6, lane = tid & 63;
    for (int j = wave; j < 9; j += 4) {
        float p = 0.f;
#pragma unroll
        for (int l = lane; l < 512; l += 64) p += h[l] * w2[j * 512 + l];
#pragma unroll
        for (int off = 32; off > 0; off >>= 1) p += __shfl_down(p, off, 64);
        if (lane == 0) out[b * 9 + j] = 1.f / (1.f + expf(-(p + b2[j])));
    }
}

// ---------------- launch ----------------
extern "C" void kernel_launch(void* const* d_in, const int* in_sizes, int n_in,
                              void* d_out, int out_size, void* d_ws, size_t ws_size,
                              hipStream_t stream) {
    const float* data   = (const float*)d_in[0];
    const float* conv_w = (const float*)d_in[1];
    const float* conv_b = (const float*)d_in[2];
    const float* pc_w   = (const float*)d_in[3];
    const float* pc_b   = (const float*)d_in[4];
    const float* W      = (const float*)d_in[5];
    const float* enc_w1 = (const float*)d_in[6];
    const float* enc_b1 = (const float*)d_in[7];
    const float* enc_w2 = (const float*)d_in[8];
    const float* enc_b2 = (const float*)d_in[9];

    char* ws = (char*)d_ws;
    bf16_t* xt    = (bf16_t*)(ws + 0);            // 104,857,600
    bf16_t* w2t   = (bf16_t*)(ws + 104857600);    //  10,616,832 -> 115,474,432
    bf16_t* parts = (bf16_t*)(ws + 115474432);    //  37,748,736 (4 x 4,718,592 bf16) -> 153,223,168
    // overlay inside parts region (used only after k_squash consumed parts):
    bf16_t* uT    = (bf16_t*)(ws + 115474432);    //   9,437,184
    bf16_t* cw2T  = (bf16_t*)(ws + 124911616);    //   2,949,120
    float*  sp    = (float*)(ws + 127860736);     //  11,796,480 -> 139,657,216
    bf16_t* ub    = (bf16_t*)(ws + 153223168);    //   9,437,184 -> 162,660,352
    float*  v     = (float*)(ws + 162660352);     //     327,680
    bf16_t* vT    = (bf16_t*)(ws + 162988032);    //     163,840
    float*  w1t   = (float*)(ws + 164200448);     //     327,680
    float*  bij   = (float*)(ws + 164528128);     //      46,080
    float*  cwt   = (float*)(ws + 164620288);     //      82,944  -> 164,703,232 total
    float*  outp  = (float*)d_out;

    hipLaunchKernelGGL(k_init_bij, dim3(45), dim3(256), 0, stream, bij);
    hipLaunchKernelGGL(k_w1t, dim3(320), dim3(256), 0, stream, enc_w1, w1t);
    hipLaunchKernelGGL(k_cwt, dim3(81), dim3(256), 0, stream, conv_w, cwt);
    hipLaunchKernelGGL(k_w2t, dim3(256), dim3(256), 0, stream, pc_w, w2t);
    hipLaunchKernelGGL(k_conv1, dim3(2048), dim3(320), 0, stream, data, cwt, conv_b, xt);
    hipLaunchKernelGGL(k_pcgemm, dim3(1152), dim3(256), 0, stream, xt, w2t, parts);
    hipLaunchKernelGGL(k_squash, dim3(512), dim3(256), 0, stream, parts, pc_b, ub);
    hipLaunchKernelGGL(k_uT, dim3(1152), dim3(256), 0, stream, ub, uT);
    for (int it = 0; it < 3; ++it) {
        hipLaunchKernelGGL(k_fold, dim3(5760), dim3(256), 0, stream, bij, W, cw2T);
        // s partials: A=ub [512][9216], B=cw2T [160][9216]; mtiles=8, ksplit=36, steps=4
        hipLaunchKernelGGL(k_rgemm, dim3(288), dim3(256), 0, stream, ub, cw2T, sp, 9216, 4, 8);
        hipLaunchKernelGGL(k_vcomp, dim3(320), dim3(256), 0, stream, sp, v, vT);
        if (it < 2) {
            hipLaunchKernelGGL(k_ggemm2, dim3(144), dim3(256), 0, stream, uT, vT, W, bij);
        }
    }
    hipLaunchKernelGGL(k_enc, dim3(512), dim3(256), 0, stream, v, w1t, enc_b1, enc_w2, enc_b2, outp);
}

// Round 6
// 442.215 us; speedup vs baseline: 3.2318x; 1.2169x over previous
//
#include <hip/hip_runtime.h>
#include <hip/hip_bf16.h>
#include <stdint.h>

// CapsNet forward. B=512, conv1 1->256 9x9 s1 (28->20), pc 256->256 9x9 s2 (20->6),
// routes R=1152, caps C=10, I=8, O=16, encoder 160->512->9.

typedef __bf16 bf16_t;
typedef __bf16 bf16x4 __attribute__((ext_vector_type(4)));
typedef __bf16 bf16x8 __attribute__((ext_vector_type(8)));
typedef float f32x4 __attribute__((ext_vector_type(4)));

__device__ __forceinline__ void gload_lds16(const void* g, void* l) {
    __builtin_amdgcn_global_load_lds((const __attribute__((address_space(1))) void*)g,
                                     (__attribute__((address_space(3))) void*)l, 16, 0, 0);
}

#define MEMBAR() asm volatile("" ::: "memory")
#define HW_BARRIER() do { MEMBAR(); __builtin_amdgcn_s_barrier(); MEMBAR(); } while (0)

// ---------------- prep kernels ----------------
__global__ void k_init_bij(float* bij) {
    int i = blockIdx.x * 256 + threadIdx.x;
    if (i < 1152 * 10) bij[i] = 0.f;
}

// enc_w1 [512][160] -> w1t [160][512]
__global__ void k_w1t(const float* __restrict__ w1, float* __restrict__ w1t) {
    int i = blockIdx.x * 256 + threadIdx.x;  // 81920
    int j = i / 160, k = i % 160;
    w1t[k * 512 + j] = w1[i];
}

// conv_w [256][81] -> Bc1 bf16 [256][104] (K padded 81->104 with zeros)
__global__ void k_w1c(const float* __restrict__ cw, bf16_t* __restrict__ Bc1) {
    int idx = blockIdx.x * 256 + threadIdx.x;  // 26624
    if (idx >= 26624) return;
    int oc = idx / 104, k = idx % 104;
    Bc1[idx] = (k < 81) ? (bf16_t)cw[oc * 81 + k] : (bf16_t)0.f;
}

// pc_w f32 [oc][ic][81] -> W2t bf16 [oc][k] with k = t*256 + ic  (t = kh*9+kw)
__global__ void k_w2t(const float* __restrict__ pcw, bf16_t* __restrict__ w2t) {
    __shared__ bf16_t tmp[20736];
    int oc = blockIdx.x;
    const float* src = pcw + (size_t)oc * 20736;
    for (int q = threadIdx.x; q < 20736; q += 256) {
        int ic = q / 81, t = q % 81;
        tmp[t * 256 + ic] = (bf16_t)src[q];
    }
    __syncthreads();
    bf16_t* dst = w2t + (size_t)oc * 20736;
    for (int q = threadIdx.x; q < 20736; q += 256) dst[q] = tmp[q];
}

// ---------------- im2col for conv1: Acol bf16 [204800][104] ----------------
// m = b*400 + oh*20 + ow ; k = kh*9+kw (<81), pad 81..103 = 0.
__global__ __launch_bounds__(256) void k_im2col(const float* __restrict__ data,
                                                bf16_t* __restrict__ Acol) {
    __shared__ float img[784];
    int b = blockIdx.x, tid = threadIdx.x;
    for (int i = tid; i < 784; i += 256) img[i] = data[b * 784 + i];
    __syncthreads();
    for (int c = tid; c < 5200; c += 256) {  // 400 pos x 13 chunks
        int pos = c / 13, kc = c % 13;
        int oh = pos / 20, ow = pos % 20;
        bf16x8 v;
#pragma unroll
        for (int j = 0; j < 8; ++j) {
            int k = kc * 8 + j;
            float x = 0.f;
            if (k < 81) {
                int kh = k / 9, kw = k % 9;
                x = img[(oh + kh) * 28 + ow + kw];
            }
            v[j] = (bf16_t)x;
        }
        *(bf16x8*)&Acol[((size_t)b * 400 + pos) * 104 + kc * 8] = v;
    }
}

// ---------------- conv1 as MFMA GEMM: xt[m][oc] = relu(Acol x Bc1^T + cb) ----------------
// M=204800 (1600 tiles of 128), N=256 (full), K=96 (3 kk; pad 81..95 zeros).
// grid 800, 2 m-tiles each; 8 waves (2m x 4n), per-wave 64x64.
// Row stride 104 bf16 = 208 B (13 x 16B chunks): 2-way bank aliasing only (free).
__global__ __launch_bounds__(512) void k_c1gemm(const bf16_t* __restrict__ Acol,
                                                const bf16_t* __restrict__ Bc1,
                                                const float* __restrict__ cb,
                                                bf16_t* __restrict__ xt) {
    __shared__ __align__(16) bf16_t As[128 * 104];  // 26,624 B
    __shared__ __align__(16) bf16_t Bs[256 * 104];  // 53,248 B
    int tid = threadIdx.x, lane = tid & 63, wave = tid >> 6;
    int wm = wave >> 2, wn = wave & 3;
    // stage B once
    for (int i = tid; i < 3328; i += 512) {
        int byte = i * 16;
        int r = byte / 208;
        int c16 = (byte - r * 208) >> 4;
        gload_lds16(Bc1 + r * 104 + c16 * 8, (char*)Bs + byte);
    }
    int mr = wm * 64 + (lane & 15);
    int nr = wn * 64 + (lane & 15);
    float bias[4];
#pragma unroll
    for (int nj = 0; nj < 4; ++nj) bias[nj] = cb[nr + nj * 16];

    for (int t = 0; t < 2; ++t) {
        int m0 = (blockIdx.x + t * 800) * 128;
        for (int i = tid; i < 1664; i += 512) {
            int byte = i * 16;
            int r = byte / 208;
            int c16 = (byte - r * 208) >> 4;
            gload_lds16(Acol + (size_t)(m0 + r) * 104 + c16 * 8, (char*)As + byte);
        }
        asm volatile("s_waitcnt vmcnt(0)" ::: "memory");
        HW_BARRIER();
        f32x4 acc[4][4];
#pragma unroll
        for (int mi = 0; mi < 4; ++mi)
#pragma unroll
            for (int nj = 0; nj < 4; ++nj) acc[mi][nj] = (f32x4){0.f, 0.f, 0.f, 0.f};
#pragma unroll
        for (int kk = 0; kk < 3; ++kk) {
            int ch = (kk * 4 + (lane >> 4)) * 8;
            bf16x8 af[4], bfr[4];
#pragma unroll
            for (int i = 0; i < 4; ++i) af[i] = *(const bf16x8*)&As[(mr + i * 16) * 104 + ch];
#pragma unroll
            for (int j = 0; j < 4; ++j) bfr[j] = *(const bf16x8*)&Bs[(nr + j * 16) * 104 + ch];
#pragma unroll
            for (int mi = 0; mi < 4; ++mi)
#pragma unroll
                for (int nj = 0; nj < 4; ++nj)
                    acc[mi][nj] = __builtin_amdgcn_mfma_f32_16x16x32_bf16(af[mi], bfr[nj], acc[mi][nj], 0, 0, 0);
        }
        int mbase = m0 + wm * 64 + (lane >> 4) * 4;
#pragma unroll
        for (int mi = 0; mi < 4; ++mi)
#pragma unroll
            for (int nj = 0; nj < 4; ++nj)
#pragma unroll
                for (int j = 0; j < 4; ++j)
                    xt[(size_t)(mbase + mi * 16 + j) * 256 + nr + nj * 16] =
                        (bf16_t)fmaxf(acc[mi][nj][j] + bias[nj], 0.f);
        HW_BARRIER();  // before next A restage
    }
}

// ---------------- PrimaryCaps implicit GEMM (R3-verified single-buffer) ----------------
// C[M=18432][N=256] = A x B ; m=b*36+pos, n=oc, k=(kh*9+kw)*256+ic
// grid 1152 = 144 m-tiles x 2 n-tiles x 4 k-splits ; tile 128x128, BK=64, 81 iters
__global__ __launch_bounds__(256) void k_pcgemm(const bf16_t* __restrict__ xt,
                                                const bf16_t* __restrict__ w2t,
                                                bf16_t* __restrict__ parts) {
    __shared__ __align__(16) bf16_t As[128 * 64];
    __shared__ __align__(16) bf16_t Bs[128 * 64];
    int bid = blockIdx.x;
    int mt = bid % 144;
    int nt = (bid / 144) & 1;
    int ks = bid / 288;  // 0..3
    int m0 = mt * 128, n0 = nt * 128;
    int tid = threadIdx.x, lane = tid & 63, wave = tid >> 6;

    int csrc = (tid & 7) ^ ((tid >> 3) & 7);  // swizzled source chunk
    int arow[4];
#pragma unroll
    for (int p = 0; p < 4; ++p) {
        int m = m0 + p * 32 + (tid >> 3);
        int bb = m / 36, pos = m % 36;
        int oh = pos / 6, ow = pos % 6;
        arow[p] = ((bb * 20 + oh * 2) * 20 + ow * 2) * 256;
    }
    const bf16_t* bbase = w2t + (size_t)(n0 + (tid >> 3)) * 20736 + csrc * 8;
    bf16_t* aldst = As + tid * 8;
    bf16_t* bldst = Bs + tid * 8;

    f32x4 acc[4][4];
#pragma unroll
    for (int mi = 0; mi < 4; ++mi)
#pragma unroll
        for (int ni = 0; ni < 4; ++ni) acc[mi][ni] = (f32x4){0.f, 0.f, 0.f, 0.f};

    int s0 = ks * 81;
    int t0 = s0 >> 2;
    int icb = s0 & 3;
    int kh = t0 / 9, kw = t0 - (t0 / 9) * 9;

    for (int it = 0; it < 81; ++it) {
        int aoff = (kh * 20 + kw) * 256 + icb * 64 + csrc * 8;
        const bf16_t* bsrc = bbase + (size_t)(s0 + it) * 64;
#pragma unroll
        for (int p = 0; p < 4; ++p) {
            gload_lds16(xt + arow[p] + aoff, aldst + p * 2048);
            gload_lds16(bsrc + (size_t)p * 32 * 20736, bldst + p * 2048);
        }
        __syncthreads();
        int mr = (wave >> 1) * 64 + (lane & 15);
        int nr = (wave & 1) * 64 + (lane & 15);
        int rx = lane & 7;
#pragma unroll
        for (int kk = 0; kk < 2; ++kk) {
            int ch = ((kk * 4 + (lane >> 4)) ^ rx) * 8;  // swizzled read chunk
            bf16x8 af[4], bfr[4];
#pragma unroll
            for (int i = 0; i < 4; ++i) af[i] = *(const bf16x8*)&As[(mr + i * 16) * 64 + ch];
#pragma unroll
            for (int i = 0; i < 4; ++i) bfr[i] = *(const bf16x8*)&Bs[(nr + i * 16) * 64 + ch];
#pragma unroll
            for (int mi = 0; mi < 4; ++mi)
#pragma unroll
                for (int ni = 0; ni < 4; ++ni)
                    acc[mi][ni] = __builtin_amdgcn_mfma_f32_16x16x32_bf16(af[mi], bfr[ni], acc[mi][ni], 0, 0, 0);
        }
        __syncthreads();
        if (++icb == 4) { icb = 0; if (++kw == 9) { kw = 0; ++kh; } }
    }

    bf16_t* out = parts + (size_t)ks * 4718592;
    int mbase = m0 + (wave >> 1) * 64 + (lane >> 4) * 4;
    int nbase = n0 + (wave & 1) * 64 + (lane & 15);
#pragma unroll
    for (int mi = 0; mi < 4; ++mi)
#pragma unroll
        for (int ni = 0; ni < 4; ++ni)
#pragma unroll
            for (int j = 0; j < 4; ++j)
                out[(size_t)(mbase + mi * 16 + j) * 256 + nbase + ni * 16] = (bf16_t)acc[mi][ni][j];
}

// ---------------- squash -> u bf16 [b][flat], flat = oc*36+pos ----------------
__global__ __launch_bounds__(256) void k_squash(const bf16_t* __restrict__ parts,
                                                const float* __restrict__ pcb,
                                                bf16_t* __restrict__ ub) {
    __shared__ float s[36 * 257];
    int b = blockIdx.x, tid = threadIdx.x;
    for (int i = tid; i < 9216; i += 256) {
        float a = pcb[i & 255];
#pragma unroll
        for (int p = 0; p < 4; ++p) a += (float)parts[(size_t)p * 4718592 + (size_t)b * 9216 + i];
        s[(i >> 8) * 257 + (i & 255)] = a;
    }
    __syncthreads();
    for (int r = tid; r < 1152; r += 256) {
        int flat0 = r * 8;
        float val[8], sn = 0.f;
#pragma unroll
        for (int e = 0; e < 8; ++e) {
            int f = flat0 + e;
            float x = s[(f % 36) * 257 + f / 36];
            val[e] = x;
            sn += x * x;
        }
        float scale = sn / ((1.f + sn) * sqrtf(sn));
        bf16x8 vv;
#pragma unroll
        for (int e = 0; e < 8; ++e) vv[e] = (bf16_t)(val[e] * scale);
        *(bf16x8*)&ub[(size_t)b * 9216 + flat0] = vv;
    }
}

// ---------------- u bf16 [512][9216] -> uT bf16 [9216][512] ----------------
__global__ __launch_bounds__(256) void k_uT(const bf16_t* __restrict__ ub, bf16_t* __restrict__ uT) {
    __shared__ bf16_t t[64 * 66];
    int kt = blockIdx.x % 144, bt = blockIdx.x / 144;
    int k0 = kt * 64, b0 = bt * 64;
    int tid = threadIdx.x;
    int c8 = tid & 7;
#pragma unroll
    for (int p = 0; p < 2; ++p) {
        int r = p * 32 + (tid >> 3);  // b-local
        bf16x8 vv = *(const bf16x8*)&ub[(size_t)(b0 + r) * 9216 + k0 + c8 * 8];
        uint32_t u4[4];
        *(bf16x8*)u4 = vv;
#pragma unroll
        for (int j2 = 0; j2 < 4; ++j2)
            *(uint32_t*)&t[r * 66 + c8 * 8 + j2 * 2] = u4[j2];
    }
    __syncthreads();
#pragma unroll
    for (int p = 0; p < 2; ++p) {
        int kp = p * 32 + (tid >> 3);  // k-local
        bf16x8 vv;
#pragma unroll
        for (int j = 0; j < 8; ++j) vv[j] = t[(c8 * 8 + j) * 66 + kp];
        *(bf16x8*)&uT[(size_t)(k0 + kp) * 512 + b0 + c8 * 8] = vv;
    }
}

// ---------------- fold + fused softmax ----------------
__global__ __launch_bounds__(256) void k_fold(const float* __restrict__ bij,
                                              const float* __restrict__ W,
                                              bf16_t* __restrict__ cw2T) {
    __shared__ float red[256];
    int idx0 = blockIdx.x * 256;
    int co = idx0 / 9216;
    int c = co >> 4, o = co & 15;
    int tid = threadIdx.x;
    float mx = -1e30f;
    for (int r = tid; r < 1152; r += 256) mx = fmaxf(mx, bij[r * 10 + c]);
    red[tid] = mx; __syncthreads();
    for (int s = 128; s > 0; s >>= 1) { if (tid < s) red[tid] = fmaxf(red[tid], red[tid + s]); __syncthreads(); }
    float mxv = red[0];
    __syncthreads();
    float sm = 0.f;
    for (int r = tid; r < 1152; r += 256) sm += expf(bij[r * 10 + c] - mxv);
    red[tid] = sm; __syncthreads();
    for (int s = 128; s > 0; s >>= 1) { if (tid < s) red[tid] += red[tid + s]; __syncthreads(); }
    float inv = 1.f / red[0];
    int k = (idx0 + tid) % 9216;
    int r = k >> 3, i = k & 7;
    float cij = expf(bij[r * 10 + c] - mxv) * inv;
    cw2T[idx0 + tid] = (bf16_t)(cij * W[((size_t)(r * 10 + c) * 16 + o) * 8 + i]);
}

// ---------------- shared NT MFMA kernel: C[M][160] = A[M][K] x B[160][K]^T ----------------
__global__ __launch_bounds__(256) void k_rgemm(const bf16_t* __restrict__ A,
                                               const bf16_t* __restrict__ B,
                                               float* __restrict__ Cp,
                                               int Kfull, int steps, int mtiles) {
    __shared__ __align__(16) bf16_t As[64 * 64];
    __shared__ __align__(16) bf16_t Bs[160 * 64];
    int bid = blockIdx.x;
    int mt = bid % mtiles, ks = bid / mtiles;
    int m0 = mt * 64;
    int k0 = ks * steps * 64;
    int tid = threadIdx.x, lane = tid & 63, wave = tid >> 6;
    int srow = tid >> 3;                       // 0..31
    int csrc = (tid & 7) ^ (srow & 7);
    const bf16_t* asrc[2];
    const bf16_t* bsrc[5];
#pragma unroll
    for (int p = 0; p < 2; ++p)
        asrc[p] = A + (size_t)(m0 + p * 32 + srow) * Kfull + k0 + csrc * 8;
#pragma unroll
    for (int p = 0; p < 5; ++p)
        bsrc[p] = B + (size_t)(p * 32 + srow) * Kfull + k0 + csrc * 8;

    f32x4 acc[2][5];
#pragma unroll
    for (int mi = 0; mi < 2; ++mi)
#pragma unroll
        for (int nj = 0; nj < 5; ++nj) acc[mi][nj] = (f32x4){0.f, 0.f, 0.f, 0.f};

    int mr = (wave >> 1) * 32 + (lane & 15);
    int nr = (wave & 1) * 80 + (lane & 15);
    int rx = lane & 7;

    for (int it = 0; it < steps; ++it) {
#pragma unroll
        for (int p = 0; p < 2; ++p) gload_lds16(asrc[p] + it * 64, As + p * 2048 + tid * 8);
#pragma unroll
        for (int p = 0; p < 5; ++p) gload_lds16(bsrc[p] + it * 64, Bs + p * 2048 + tid * 8);
        __syncthreads();
#pragma unroll
        for (int kk = 0; kk < 2; ++kk) {
            int ch = ((kk * 4 + (lane >> 4)) ^ rx) * 8;
            bf16x8 af[2], bfr[5];
#pragma unroll
            for (int i = 0; i < 2; ++i) af[i] = *(const bf16x8*)&As[(mr + i * 16) * 64 + ch];
#pragma unroll
            for (int j = 0; j < 5; ++j) bfr[j] = *(const bf16x8*)&Bs[(nr + j * 16) * 64 + ch];
#pragma unroll
            for (int mi = 0; mi < 2; ++mi)
#pragma unroll
                for (int nj = 0; nj < 5; ++nj)
                    acc[mi][nj] = __builtin_amdgcn_mfma_f32_16x16x32_bf16(af[mi], bfr[nj], acc[mi][nj], 0, 0, 0);
        }
        __syncthreads();
    }

    float* out = Cp + (size_t)ks * ((size_t)mtiles * 64 * 160);
    int mbase = m0 + (wave >> 1) * 32 + (lane >> 4) * 4;
    int nbase = (wave & 1) * 80 + (lane & 15);
#pragma unroll
    for (int mi = 0; mi < 2; ++mi)
#pragma unroll
        for (int nj = 0; nj < 5; ++nj)
#pragma unroll
            for (int j = 0; j < 4; ++j)
                out[(size_t)(mbase + mi * 16 + j) * 160 + nbase + nj * 16] = acc[mi][nj][j];
}

// ---------------- v + vT from s partials ----------------
__global__ void k_vcomp(const float* __restrict__ sp, float* __restrict__ v,
                        bf16_t* __restrict__ vT) {
    int idx = blockIdx.x * 256 + threadIdx.x;  // 81920
    float s = 0.f;
#pragma unroll
    for (int p = 0; p < 36; ++p) s += sp[(size_t)p * 81920 + idx];
    float val = s * fabsf(s) / (1.f + s * s);
    v[idx] = val;
    int b = idx / 160, co = idx % 160;
    vT[(size_t)co * 512 + b] = (bf16_t)val;
}

// ---------------- G-gemm + amean fused ----------------
__global__ __launch_bounds__(256) void k_ggemm2(const bf16_t* __restrict__ uT,
                                                const bf16_t* __restrict__ vT,
                                                const float* __restrict__ W,
                                                float* __restrict__ bij) {
    __shared__ __align__(16) bf16_t As[64 * 64];
    __shared__ __align__(16) bf16_t Bs[160 * 64];
    __shared__ float Gl[64 * 161];
    int mt = blockIdx.x;
    int m0 = mt * 64;
    int tid = threadIdx.x, lane = tid & 63, wave = tid >> 6;
    int srow = tid >> 3;
    int csrc = (tid & 7) ^ (srow & 7);
    const bf16_t* asrc[2];
    const bf16_t* bsrc[5];
#pragma unroll
    for (int p = 0; p < 2; ++p)
        asrc[p] = uT + (size_t)(m0 + p * 32 + srow) * 512 + csrc * 8;
#pragma unroll
    for (int p = 0; p < 5; ++p)
        bsrc[p] = vT + (size_t)(p * 32 + srow) * 512 + csrc * 8;

    f32x4 acc[2][5];
#pragma unroll
    for (int mi = 0; mi < 2; ++mi)
#pragma unroll
        for (int nj = 0; nj < 5; ++nj) acc[mi][nj] = (f32x4){0.f, 0.f, 0.f, 0.f};

    int mr = (wave >> 1) * 32 + (lane & 15);
    int nr = (wave & 1) * 80 + (lane & 15);
    int rx = lane & 7;

    for (int it = 0; it < 8; ++it) {
#pragma unroll
        for (int p = 0; p < 2; ++p) gload_lds16(asrc[p] + it * 64, As + p * 2048 + tid * 8);
#pragma unroll
        for (int p = 0; p < 5; ++p) gload_lds16(bsrc[p] + it * 64, Bs + p * 2048 + tid * 8);
        __syncthreads();
#pragma unroll
        for (int kk = 0; kk < 2; ++kk) {
            int ch = ((kk * 4 + (lane >> 4)) ^ rx) * 8;
            bf16x8 af[2], bfr[5];
#pragma unroll
            for (int i = 0; i < 2; ++i) af[i] = *(const bf16x8*)&As[(mr + i * 16) * 64 + ch];
#pragma unroll
            for (int j = 0; j < 5; ++j) bfr[j] = *(const bf16x8*)&Bs[(nr + j * 16) * 64 + ch];
#pragma unroll
            for (int mi = 0; mi < 2; ++mi)
#pragma unroll
                for (int nj = 0; nj < 5; ++nj)
                    acc[mi][nj] = __builtin_amdgcn_mfma_f32_16x16x32_bf16(af[mi], bfr[nj], acc[mi][nj], 0, 0, 0);
        }
        __syncthreads();
    }

    int mbl = (wave >> 1) * 32 + (lane >> 4) * 4;
    int nbase = (wave & 1) * 80 + (lane & 15);
#pragma unroll
    for (int mi = 0; mi < 2; ++mi)
#pragma unroll
        for (int nj = 0; nj < 5; ++nj)
#pragma unroll
            for (int j = 0; j < 4; ++j)
                Gl[(mbl + mi * 16 + j) * 161 + nbase + nj * 16] = acc[mi][nj][j] * (1.0f / 512.0f);
    __syncthreads();
    if (tid < 80) {
        int rl = tid / 10, c = tid % 10;
        int r = mt * 8 + rl;
        const float* wbase = W + (size_t)(r * 10 + c) * 128;
        float s = 0.f;
#pragma unroll
        for (int o = 0; o < 16; ++o)
#pragma unroll
            for (int i = 0; i < 8; ++i)
                s += wbase[o * 8 + i] * Gl[(rl * 8 + i) * 161 + c * 16 + o];
        bij[r * 10 + c] += s;
    }
}

// ---------------- encoder (enc1+enc2 fused) ----------------
__global__ __launch_bounds__(256) void k_enc(const float* __restrict__ v,
                                             const float* __restrict__ w1t,
                                             const float* __restrict__ b1,
                                             const float* __restrict__ w2,
                                             const float* __restrict__ b2,
                                             float* __restrict__ out) {
    __shared__ float fl[160];
    __shared__ float h[512];
    int b = blockIdx.x, tid = threadIdx.x;
    if (tid < 160) fl[tid] = v[b * 160 + tid];
    __syncthreads();
    for (int j = tid; j < 512; j += 256) {
        float s = b1[j];
#pragma unroll 8
        for (int k = 0; k < 160; ++k) s += fl[k] * w1t[k * 512 + j];
        h[j] = fmaxf(s, 0.f);
    }
    __syncthreads();
    int wave = tid >> 6, lane = tid & 63;
    for (int j = wave; j < 9; j += 4) {
        float p = 0.f;
#pragma unroll
        for (int l = lane; l < 512; l += 64) p += h[l] * w2[j * 512 + l];
#pragma unroll
        for (int off = 32; off > 0; off >>= 1) p += __shfl_down(p, off, 64);
        if (lane == 0) out[b * 9 + j] = 1.f / (1.f + expf(-(p + b2[j])));
    }
}

// ---------------- launch ----------------
extern "C" void kernel_launch(void* const* d_in, const int* in_sizes, int n_in,
                              void* d_out, int out_size, void* d_ws, size_t ws_size,
                              hipStream_t stream) {
    const float* data   = (const float*)d_in[0];
    const float* conv_w = (const float*)d_in[1];
    const float* conv_b = (const float*)d_in[2];
    const float* pc_w   = (const float*)d_in[3];
    const float* pc_b   = (const float*)d_in[4];
    const float* W      = (const float*)d_in[5];
    const float* enc_w1 = (const float*)d_in[6];
    const float* enc_b1 = (const float*)d_in[7];
    const float* enc_w2 = (const float*)d_in[8];
    const float* enc_b2 = (const float*)d_in[9];

    char* ws = (char*)d_ws;
    bf16_t* xt    = (bf16_t*)(ws + 0);            // 104,857,600
    bf16_t* w2t   = (bf16_t*)(ws + 104857600);    //  10,616,832 -> 115,474,432
    bf16_t* parts = (bf16_t*)(ws + 115474432);    //  37,748,736 (4 x 4,718,592 bf16) -> 153,223,168
    // overlays (each region dead when its tenant runs):
    bf16_t* Acol  = (bf16_t*)(ws + 115474432);    //  42,598,400 (dead after k_c1gemm; before pcgemm)
    bf16_t* uT    = (bf16_t*)(ws + 115474432);    //   9,437,184 (after squash)
    bf16_t* cw2T  = (bf16_t*)(ws + 124911616);    //   2,949,120
    float*  sp    = (float*)(ws + 127860736);     //  11,796,480 -> 139,657,216
    bf16_t* ub    = (bf16_t*)(ws + 153223168);    //   9,437,184 -> 162,660,352
    float*  v     = (float*)(ws + 162660352);     //     327,680
    bf16_t* vT    = (bf16_t*)(ws + 162988032);    //     163,840
    float*  w1t   = (float*)(ws + 164200448);     //     327,680
    float*  bij   = (float*)(ws + 164528128);     //      46,080
    bf16_t* Bc1   = (bf16_t*)(ws + 164620288);    //      53,248 -> 164,673,536 total
    float*  outp  = (float*)d_out;

    hipLaunchKernelGGL(k_init_bij, dim3(45), dim3(256), 0, stream, bij);
    hipLaunchKernelGGL(k_w1t, dim3(320), dim3(256), 0, stream, enc_w1, w1t);
    hipLaunchKernelGGL(k_w1c, dim3(104), dim3(256), 0, stream, conv_w, Bc1);
    hipLaunchKernelGGL(k_w2t, dim3(256), dim3(256), 0, stream, pc_w, w2t);
    hipLaunchKernelGGL(k_im2col, dim3(512), dim3(256), 0, stream, data, Acol);
    hipLaunchKernelGGL(k_c1gemm, dim3(800), dim3(512), 0, stream, Acol, Bc1, conv_b, xt);
    hipLaunchKernelGGL(k_pcgemm, dim3(1152), dim3(256), 0, stream, xt, w2t, parts);
    hipLaunchKernelGGL(k_squash, dim3(512), dim3(256), 0, stream, parts, pc_b, ub);
    hipLaunchKernelGGL(k_uT, dim3(1152), dim3(256), 0, stream, ub, uT);
    for (int it = 0; it < 3; ++it) {
        hipLaunchKernelGGL(k_fold, dim3(5760), dim3(256), 0, stream, bij, W, cw2T);
        hipLaunchKernelGGL(k_rgemm, dim3(288), dim3(256), 0, stream, ub, cw2T, sp, 9216, 4, 8);
        hipLaunchKernelGGL(k_vcomp, dim3(320), dim3(256), 0, stream, sp, v, vT);
        if (it < 2) {
            hipLaunchKernelGGL(k_ggemm2, dim3(144), dim3(256), 0, stream, uT, vT, W, bij);
        }
    }
    hipLaunchKernelGGL(k_enc, dim3(512), dim3(256), 0, stream, v, w1t, enc_b1, enc_w2, enc_b2, outp);
}

// Round 7
// 331.263 us; speedup vs baseline: 4.3143x; 1.3349x over previous
//
#include <hip/hip_runtime.h>
#include <hip/hip_bf16.h>
#include <stdint.h>

// CapsNet forward. B=512, conv1 1->256 9x9 s1 (28->20), pc 256->256 9x9 s2 (20->6),
// routes R=1152, caps C=10, I=8, O=16, encoder 160->512->9.
// R7: pcgemm in MX-fp8 (mfma_scale 16x16x128, constant scales A=2^0, B=2^-6).

typedef __bf16 bf16_t;
typedef __bf16 bf16x4 __attribute__((ext_vector_type(4)));
typedef __bf16 bf16x8 __attribute__((ext_vector_type(8)));
typedef float f32x4 __attribute__((ext_vector_type(4)));
typedef int i32x4 __attribute__((ext_vector_type(4)));
typedef int i32x8 __attribute__((ext_vector_type(8)));

__device__ __forceinline__ void gload_lds16(const void* g, void* l) {
    __builtin_amdgcn_global_load_lds((const __attribute__((address_space(1))) void*)g,
                                     (__attribute__((address_space(3))) void*)l, 16, 0, 0);
}

#define MEMBAR() asm volatile("" ::: "memory")
#define HW_BARRIER() do { MEMBAR(); __builtin_amdgcn_s_barrier(); MEMBAR(); } while (0)

// f32 -> e4m3 byte (RNE via v_cvt_pk_fp8_f32)
__device__ __forceinline__ uint8_t fp8b(float v) {
    return (uint8_t)(__builtin_amdgcn_cvt_pk_fp8_f32(v, 0.f, 0, false) & 0xFF);
}

// ---------------- prep kernels ----------------
__global__ void k_init_bij(float* bij) {
    int i = blockIdx.x * 256 + threadIdx.x;
    if (i < 1152 * 10) bij[i] = 0.f;
}

// enc_w1 [512][160] -> w1t [160][512]
__global__ void k_w1t(const float* __restrict__ w1, float* __restrict__ w1t) {
    int i = blockIdx.x * 256 + threadIdx.x;  // 81920
    int j = i / 160, k = i % 160;
    w1t[k * 512 + j] = w1[i];
}

// conv_w [256][81] -> Bc1 bf16 [256][104] (K padded 81->104 with zeros)
__global__ void k_w1c(const float* __restrict__ cw, bf16_t* __restrict__ Bc1) {
    int idx = blockIdx.x * 256 + threadIdx.x;  // 26624
    if (idx >= 26624) return;
    int oc = idx / 104, k = idx % 104;
    Bc1[idx] = (k < 81) ? (bf16_t)cw[oc * 81 + k] : (bf16_t)0.f;
}

// pc_w f32 [oc][ic][81] -> w2t8 fp8 [oc][k], k = t*256 + ic, value = fp8(pc_w * 64)
__global__ __launch_bounds__(256) void k_w2t(const float* __restrict__ pcw,
                                             uint8_t* __restrict__ w2t8) {
    __shared__ uint16_t tmp16[10368];  // fp8 pairs in SOURCE order (ic*81+t)
    int oc = blockIdx.x, tid = threadIdx.x;
    const float* src = pcw + (size_t)oc * 20736;
    for (int q2 = tid; q2 < 10368; q2 += 256) {
        float a = src[q2 * 2] * 64.f;
        float b = src[q2 * 2 + 1] * 64.f;
        uint32_t pk = __builtin_amdgcn_cvt_pk_fp8_f32(a, b, 0, false);
        tmp16[q2] = (uint16_t)(pk & 0xFFFF);
    }
    __syncthreads();
    uint32_t* dst = (uint32_t*)(w2t8 + (size_t)oc * 20736);
    for (int w = tid; w < 5184; w += 256) {  // out word = k 4w..4w+3
        int k = w * 4;
        int t = k >> 8, ic0 = k & 255;
        uint32_t r = 0;
#pragma unroll
        for (int j = 0; j < 4; ++j) {
            int s = (ic0 + j) * 81 + t;  // source index
            uint32_t b = (tmp16[s >> 1] >> ((s & 1) * 8)) & 0xFF;
            r |= b << (8 * j);
        }
        dst[w] = r;
    }
}

// ---------------- im2col for conv1: Acol bf16 [204800][104] ----------------
__global__ __launch_bounds__(256) void k_im2col(const float* __restrict__ data,
                                                bf16_t* __restrict__ Acol) {
    __shared__ float img[784];
    int b = blockIdx.x, tid = threadIdx.x;
    for (int i = tid; i < 784; i += 256) img[i] = data[b * 784 + i];
    __syncthreads();
    for (int c = tid; c < 5200; c += 256) {  // 400 pos x 13 chunks
        int pos = c / 13, kc = c % 13;
        int oh = pos / 20, ow = pos % 20;
        bf16x8 v;
#pragma unroll
        for (int j = 0; j < 8; ++j) {
            int k = kc * 8 + j;
            float x = 0.f;
            if (k < 81) {
                int kh = k / 9, kw = k % 9;
                x = img[(oh + kh) * 28 + ow + kw];
            }
            v[j] = (bf16_t)x;
        }
        *(bf16x8*)&Acol[((size_t)b * 400 + pos) * 104 + kc * 8] = v;
    }
}

// ---------------- conv1 as MFMA GEMM -> xt8 fp8 [m][256] ----------------
__global__ __launch_bounds__(512) void k_c1gemm(const bf16_t* __restrict__ Acol,
                                                const bf16_t* __restrict__ Bc1,
                                                const float* __restrict__ cb,
                                                uint8_t* __restrict__ xt8) {
    __shared__ __align__(16) bf16_t As[128 * 104];  // 26,624 B
    __shared__ __align__(16) bf16_t Bs[256 * 104];  // 53,248 B
    int tid = threadIdx.x, lane = tid & 63, wave = tid >> 6;
    int wm = wave >> 2, wn = wave & 3;
    for (int i = tid; i < 3328; i += 512) {
        int byte = i * 16;
        int r = byte / 208;
        int c16 = (byte - r * 208) >> 4;
        gload_lds16(Bc1 + r * 104 + c16 * 8, (char*)Bs + byte);
    }
    int mr = wm * 64 + (lane & 15);
    int nr = wn * 64 + (lane & 15);
    float bias[4];
#pragma unroll
    for (int nj = 0; nj < 4; ++nj) bias[nj] = cb[nr + nj * 16];

    for (int t = 0; t < 2; ++t) {
        int m0 = (blockIdx.x + t * 800) * 128;
        for (int i = tid; i < 1664; i += 512) {
            int byte = i * 16;
            int r = byte / 208;
            int c16 = (byte - r * 208) >> 4;
            gload_lds16(Acol + (size_t)(m0 + r) * 104 + c16 * 8, (char*)As + byte);
        }
        asm volatile("s_waitcnt vmcnt(0)" ::: "memory");
        HW_BARRIER();
        f32x4 acc[4][4];
#pragma unroll
        for (int mi = 0; mi < 4; ++mi)
#pragma unroll
            for (int nj = 0; nj < 4; ++nj) acc[mi][nj] = (f32x4){0.f, 0.f, 0.f, 0.f};
#pragma unroll
        for (int kk = 0; kk < 3; ++kk) {
            int ch = (kk * 4 + (lane >> 4)) * 8;
            bf16x8 af[4], bfr[4];
#pragma unroll
            for (int i = 0; i < 4; ++i) af[i] = *(const bf16x8*)&As[(mr + i * 16) * 104 + ch];
#pragma unroll
            for (int j = 0; j < 4; ++j) bfr[j] = *(const bf16x8*)&Bs[(nr + j * 16) * 104 + ch];
#pragma unroll
            for (int mi = 0; mi < 4; ++mi)
#pragma unroll
                for (int nj = 0; nj < 4; ++nj)
                    acc[mi][nj] = __builtin_amdgcn_mfma_f32_16x16x32_bf16(af[mi], bfr[nj], acc[mi][nj], 0, 0, 0);
        }
        int mbase = m0 + wm * 64 + (lane >> 4) * 4;
#pragma unroll
        for (int mi = 0; mi < 4; ++mi)
#pragma unroll
            for (int nj = 0; nj < 4; ++nj)
#pragma unroll
                for (int j = 0; j < 4; ++j)
                    xt8[(size_t)(mbase + mi * 16 + j) * 256 + nr + nj * 16] =
                        fp8b(fmaxf(acc[mi][nj][j] + bias[nj], 0.f));
        HW_BARRIER();
    }
}

// ---------------- PrimaryCaps implicit GEMM, MX-fp8 (m97 structure, K=128/step) ----------------
// C[M=18432][N=256] = A x B ; m=b*36+pos, n=oc, k=(kh*9+kw)*256+ic (bytes)
// grid 576 = 144 m-tiles x 2 n-tiles x 2 k-splits ; tile 128x128, BK=128 B, 81 steps.
// Same 128-B-row LDS geometry + XOR chunk swizzle as the verified bf16 kernel.
// Scales: A = 2^0 (0x7F), B = 2^-6 (0x79, undoes the x64 in w2t8).
__global__ __launch_bounds__(256) void k_pcgemm(const uint8_t* __restrict__ xt8,
                                                const uint8_t* __restrict__ w2t8,
                                                bf16_t* __restrict__ parts) {
    __shared__ __align__(16) uint8_t As[128 * 128];
    __shared__ __align__(16) uint8_t Bs[128 * 128];
    int bid = blockIdx.x;
    int mt = bid % 144;
    int nt = (bid / 144) & 1;
    int ks = bid / 288;  // 0..1
    int m0 = mt * 128, n0 = nt * 128;
    int tid = threadIdx.x, lane = tid & 63, wave = tid >> 6;

    int csrc = (tid & 7) ^ ((tid >> 3) & 7);  // swizzled source chunk (16-B units)
    int arow[4];
#pragma unroll
    for (int p = 0; p < 4; ++p) {
        int m = m0 + p * 32 + (tid >> 3);
        int bb = m / 36, pos = m % 36;
        int oh = pos / 6, ow = pos % 6;
        arow[p] = ((bb * 20 + oh * 2) * 20 + ow * 2) * 256;
    }
    const uint8_t* bbase = w2t8 + (size_t)(n0 + (tid >> 3)) * 20736 + csrc * 16;

    f32x4 acc[4][4];
#pragma unroll
    for (int mi = 0; mi < 4; ++mi)
#pragma unroll
        for (int ni = 0; ni < 4; ++ni) acc[mi][ni] = (f32x4){0.f, 0.f, 0.f, 0.f};

    int g0 = ks * 81;
    int mr = (wave >> 1) * 64 + (lane & 15);
    int nr = (wave & 1) * 64 + (lane & 15);
    int rx = lane & 7;
    int c0 = (2 * (lane >> 4)) ^ rx;
    int c1 = (2 * (lane >> 4) + 1) ^ rx;

    for (int it = 0; it < 81; ++it) {
        int g = g0 + it;
        int t = g >> 1, icb = g & 1;
        int kh = t / 9, kw = t - (t / 9) * 9;
        int aoff = (kh * 20 + kw) * 256 + icb * 128 + csrc * 16;
#pragma unroll
        for (int p = 0; p < 4; ++p) {
            gload_lds16(xt8 + arow[p] + aoff, &As[p * 4096 + tid * 16]);
            gload_lds16(bbase + (size_t)p * 32 * 20736 + (size_t)g * 128, &Bs[p * 4096 + tid * 16]);
        }
        __syncthreads();
        i32x8 af[4], bfr[4];
#pragma unroll
        for (int i = 0; i < 4; ++i) {
            i32x4 lo = *(const i32x4*)&As[(mr + i * 16) * 128 + c0 * 16];
            i32x4 hi = *(const i32x4*)&As[(mr + i * 16) * 128 + c1 * 16];
            af[i][0] = lo[0]; af[i][1] = lo[1]; af[i][2] = lo[2]; af[i][3] = lo[3];
            af[i][4] = hi[0]; af[i][5] = hi[1]; af[i][6] = hi[2]; af[i][7] = hi[3];
        }
#pragma unroll
        for (int i = 0; i < 4; ++i) {
            i32x4 lo = *(const i32x4*)&Bs[(nr + i * 16) * 128 + c0 * 16];
            i32x4 hi = *(const i32x4*)&Bs[(nr + i * 16) * 128 + c1 * 16];
            bfr[i][0] = lo[0]; bfr[i][1] = lo[1]; bfr[i][2] = lo[2]; bfr[i][3] = lo[3];
            bfr[i][4] = hi[0]; bfr[i][5] = hi[1]; bfr[i][6] = hi[2]; bfr[i][7] = hi[3];
        }
#pragma unroll
        for (int mi = 0; mi < 4; ++mi)
#pragma unroll
            for (int ni = 0; ni < 4; ++ni)
                acc[mi][ni] = __builtin_amdgcn_mfma_scale_f32_16x16x128_f8f6f4(
                    af[mi], bfr[ni], acc[mi][ni], 0, 0, 0, 0x7F7F7F7F, 0, 0x79797979);
        __syncthreads();
    }

    bf16_t* out = parts + (size_t)ks * 4718592;
    int mbase = m0 + (wave >> 1) * 64 + (lane >> 4) * 4;
    int nbase = n0 + (wave & 1) * 64 + (lane & 15);
#pragma unroll
    for (int mi = 0; mi < 4; ++mi)
#pragma unroll
        for (int ni = 0; ni < 4; ++ni)
#pragma unroll
            for (int j = 0; j < 4; ++j)
                out[(size_t)(mbase + mi * 16 + j) * 256 + nbase + ni * 16] = (bf16_t)acc[mi][ni][j];
}

// ---------------- squash -> u bf16 [b][flat], flat = oc*36+pos ----------------
__global__ __launch_bounds__(256) void k_squash(const bf16_t* __restrict__ parts,
                                                const float* __restrict__ pcb,
                                                bf16_t* __restrict__ ub) {
    __shared__ float s[36 * 257];
    int b = blockIdx.x, tid = threadIdx.x;
    for (int i = tid; i < 9216; i += 256) {
        float a = pcb[i & 255];
#pragma unroll
        for (int p = 0; p < 2; ++p) a += (float)parts[(size_t)p * 4718592 + (size_t)b * 9216 + i];
        s[(i >> 8) * 257 + (i & 255)] = a;
    }
    __syncthreads();
    for (int r = tid; r < 1152; r += 256) {
        int flat0 = r * 8;
        float val[8], sn = 0.f;
#pragma unroll
        for (int e = 0; e < 8; ++e) {
            int f = flat0 + e;
            float x = s[(f % 36) * 257 + f / 36];
            val[e] = x;
            sn += x * x;
        }
        float scale = sn / ((1.f + sn) * sqrtf(sn));
        bf16x8 vv;
#pragma unroll
        for (int e = 0; e < 8; ++e) vv[e] = (bf16_t)(val[e] * scale);
        *(bf16x8*)&ub[(size_t)b * 9216 + flat0] = vv;
    }
}

// ---------------- u bf16 [512][9216] -> uT bf16 [9216][512] ----------------
__global__ __launch_bounds__(256) void k_uT(const bf16_t* __restrict__ ub, bf16_t* __restrict__ uT) {
    __shared__ bf16_t t[64 * 66];
    int kt = blockIdx.x % 144, bt = blockIdx.x / 144;
    int k0 = kt * 64, b0 = bt * 64;
    int tid = threadIdx.x;
    int c8 = tid & 7;
#pragma unroll
    for (int p = 0; p < 2; ++p) {
        int r = p * 32 + (tid >> 3);  // b-local
        bf16x8 vv = *(const bf16x8*)&ub[(size_t)(b0 + r) * 9216 + k0 + c8 * 8];
        uint32_t u4[4];
        *(bf16x8*)u4 = vv;
#pragma unroll
        for (int j2 = 0; j2 < 4; ++j2)
            *(uint32_t*)&t[r * 66 + c8 * 8 + j2 * 2] = u4[j2];
    }
    __syncthreads();
#pragma unroll
    for (int p = 0; p < 2; ++p) {
        int kp = p * 32 + (tid >> 3);  // k-local
        bf16x8 vv;
#pragma unroll
        for (int j = 0; j < 8; ++j) vv[j] = t[(c8 * 8 + j) * 66 + kp];
        *(bf16x8*)&uT[(size_t)(k0 + kp) * 512 + b0 + c8 * 8] = vv;
    }
}

// ---------------- fold + fused softmax ----------------
__global__ __launch_bounds__(256) void k_fold(const float* __restrict__ bij,
                                              const float* __restrict__ W,
                                              bf16_t* __restrict__ cw2T) {
    __shared__ float red[256];
    int idx0 = blockIdx.x * 256;
    int co = idx0 / 9216;
    int c = co >> 4, o = co & 15;
    int tid = threadIdx.x;
    float mx = -1e30f;
    for (int r = tid; r < 1152; r += 256) mx = fmaxf(mx, bij[r * 10 + c]);
    red[tid] = mx; __syncthreads();
    for (int s = 128; s > 0; s >>= 1) { if (tid < s) red[tid] = fmaxf(red[tid], red[tid + s]); __syncthreads(); }
    float mxv = red[0];
    __syncthreads();
    float sm = 0.f;
    for (int r = tid; r < 1152; r += 256) sm += expf(bij[r * 10 + c] - mxv);
    red[tid] = sm; __syncthreads();
    for (int s = 128; s > 0; s >>= 1) { if (tid < s) red[tid] += red[tid + s]; __syncthreads(); }
    float inv = 1.f / red[0];
    int k = (idx0 + tid) % 9216;
    int r = k >> 3, i = k & 7;
    float cij = expf(bij[r * 10 + c] - mxv) * inv;
    cw2T[idx0 + tid] = (bf16_t)(cij * W[((size_t)(r * 10 + c) * 16 + o) * 8 + i]);
}

// ---------------- shared NT MFMA kernel: C[M][160] = A[M][K] x B[160][K]^T ----------------
__global__ __launch_bounds__(256) void k_rgemm(const bf16_t* __restrict__ A,
                                               const bf16_t* __restrict__ B,
                                               float* __restrict__ Cp,
                                               int Kfull, int steps, int mtiles) {
    __shared__ __align__(16) bf16_t As[64 * 64];
    __shared__ __align__(16) bf16_t Bs[160 * 64];
    int bid = blockIdx.x;
    int mt = bid % mtiles, ks = bid / mtiles;
    int m0 = mt * 64;
    int k0 = ks * steps * 64;
    int tid = threadIdx.x, lane = tid & 63, wave = tid >> 6;
    int srow = tid >> 3;                       // 0..31
    int csrc = (tid & 7) ^ (srow & 7);
    const bf16_t* asrc[2];
    const bf16_t* bsrc[5];
#pragma unroll
    for (int p = 0; p < 2; ++p)
        asrc[p] = A + (size_t)(m0 + p * 32 + srow) * Kfull + k0 + csrc * 8;
#pragma unroll
    for (int p = 0; p < 5; ++p)
        bsrc[p] = B + (size_t)(p * 32 + srow) * Kfull + k0 + csrc * 8;

    f32x4 acc[2][5];
#pragma unroll
    for (int mi = 0; mi < 2; ++mi)
#pragma unroll
        for (int nj = 0; nj < 5; ++nj) acc[mi][nj] = (f32x4){0.f, 0.f, 0.f, 0.f};

    int mr = (wave >> 1) * 32 + (lane & 15);
    int nr = (wave & 1) * 80 + (lane & 15);
    int rx = lane & 7;

    for (int it = 0; it < steps; ++it) {
#pragma unroll
        for (int p = 0; p < 2; ++p) gload_lds16(asrc[p] + it * 64, As + p * 2048 + tid * 8);
#pragma unroll
        for (int p = 0; p < 5; ++p) gload_lds16(bsrc[p] + it * 64, Bs + p * 2048 + tid * 8);
        __syncthreads();
#pragma unroll
        for (int kk = 0; kk < 2; ++kk) {
            int ch = ((kk * 4 + (lane >> 4)) ^ rx) * 8;
            bf16x8 af[2], bfr[5];
#pragma unroll
            for (int i = 0; i < 2; ++i) af[i] = *(const bf16x8*)&As[(mr + i * 16) * 64 + ch];
#pragma unroll
            for (int j = 0; j < 5; ++j) bfr[j] = *(const bf16x8*)&Bs[(nr + j * 16) * 64 + ch];
#pragma unroll
            for (int mi = 0; mi < 2; ++mi)
#pragma unroll
                for (int nj = 0; nj < 5; ++nj)
                    acc[mi][nj] = __builtin_amdgcn_mfma_f32_16x16x32_bf16(af[mi], bfr[nj], acc[mi][nj], 0, 0, 0);
        }
        __syncthreads();
    }

    float* out = Cp + (size_t)ks * ((size_t)mtiles * 64 * 160);
    int mbase = m0 + (wave >> 1) * 32 + (lane >> 4) * 4;
    int nbase = (wave & 1) * 80 + (lane & 15);
#pragma unroll
    for (int mi = 0; mi < 2; ++mi)
#pragma unroll
        for (int nj = 0; nj < 5; ++nj)
#pragma unroll
            for (int j = 0; j < 4; ++j)
                out[(size_t)(mbase + mi * 16 + j) * 160 + nbase + nj * 16] = acc[mi][nj][j];
}

// ---------------- v + vT from s partials ----------------
__global__ void k_vcomp(const float* __restrict__ sp, float* __restrict__ v,
                        bf16_t* __restrict__ vT) {
    int idx = blockIdx.x * 256 + threadIdx.x;  // 81920
    float s = 0.f;
#pragma unroll
    for (int p = 0; p < 36; ++p) s += sp[(size_t)p * 81920 + idx];
    float val = s * fabsf(s) / (1.f + s * s);
    v[idx] = val;
    int b = idx / 160, co = idx % 160;
    vT[(size_t)co * 512 + b] = (bf16_t)val;
}

// ---------------- G-gemm + amean fused ----------------
__global__ __launch_bounds__(256) void k_ggemm2(const bf16_t* __restrict__ uT,
                                                const bf16_t* __restrict__ vT,
                                                const float* __restrict__ W,
                                                float* __restrict__ bij) {
    __shared__ __align__(16) bf16_t As[64 * 64];
    __shared__ __align__(16) bf16_t Bs[160 * 64];
    __shared__ float Gl[64 * 161];
    int mt = blockIdx.x;
    int m0 = mt * 64;
    int tid = threadIdx.x, lane = tid & 63, wave = tid >> 6;
    int srow = tid >> 3;
    int csrc = (tid & 7) ^ (srow & 7);
    const bf16_t* asrc[2];
    const bf16_t* bsrc[5];
#pragma unroll
    for (int p = 0; p < 2; ++p)
        asrc[p] = uT + (size_t)(m0 + p * 32 + srow) * 512 + csrc * 8;
#pragma unroll
    for (int p = 0; p < 5; ++p)
        bsrc[p] = vT + (size_t)(p * 32 + srow) * 512 + csrc * 8;

    f32x4 acc[2][5];
#pragma unroll
    for (int mi = 0; mi < 2; ++mi)
#pragma unroll
        for (int nj = 0; nj < 5; ++nj) acc[mi][nj] = (f32x4){0.f, 0.f, 0.f, 0.f};

    int mr = (wave >> 1) * 32 + (lane & 15);
    int nr = (wave & 1) * 80 + (lane & 15);
    int rx = lane & 7;

    for (int it = 0; it < 8; ++it) {
#pragma unroll
        for (int p = 0; p < 2; ++p) gload_lds16(asrc[p] + it * 64, As + p * 2048 + tid * 8);
#pragma unroll
        for (int p = 0; p < 5; ++p) gload_lds16(bsrc[p] + it * 64, Bs + p * 2048 + tid * 8);
        __syncthreads();
#pragma unroll
        for (int kk = 0; kk < 2; ++kk) {
            int ch = ((kk * 4 + (lane >> 4)) ^ rx) * 8;
            bf16x8 af[2], bfr[5];
#pragma unroll
            for (int i = 0; i < 2; ++i) af[i] = *(const bf16x8*)&As[(mr + i * 16) * 64 + ch];
#pragma unroll
            for (int j = 0; j < 5; ++j) bfr[j] = *(const bf16x8*)&Bs[(nr + j * 16) * 64 + ch];
#pragma unroll
            for (int mi = 0; mi < 2; ++mi)
#pragma unroll
                for (int nj = 0; nj < 5; ++nj)
                    acc[mi][nj] = __builtin_amdgcn_mfma_f32_16x16x32_bf16(af[mi], bfr[nj], acc[mi][nj], 0, 0, 0);
        }
        __syncthreads();
    }

    int mbl = (wave >> 1) * 32 + (lane >> 4) * 4;
    int nbase = (wave & 1) * 80 + (lane & 15);
#pragma unroll
    for (int mi = 0; mi < 2; ++mi)
#pragma unroll
        for (int nj = 0; nj < 5; ++nj)
#pragma unroll
            for (int j = 0; j < 4; ++j)
                Gl[(mbl + mi * 16 + j) * 161 + nbase + nj * 16] = acc[mi][nj][j] * (1.0f / 512.0f);
    __syncthreads();
    if (tid < 80) {
        int rl = tid / 10, c = tid % 10;
        int r = mt * 8 + rl;
        const float* wbase = W + (size_t)(r * 10 + c) * 128;
        float s = 0.f;
#pragma unroll
        for (int o = 0; o < 16; ++o)
#pragma unroll
            for (int i = 0; i < 8; ++i)
                s += wbase[o * 8 + i] * Gl[(rl * 8 + i) * 161 + c * 16 + o];
        bij[r * 10 + c] += s;
    }
}

// ---------------- encoder (enc1+enc2 fused) ----------------
__global__ __launch_bounds__(256) void k_enc(const float* __restrict__ v,
                                             const float* __restrict__ w1t,
                                             const float* __restrict__ b1,
                                             const float* __restrict__ w2,
                                             const float* __restrict__ b2,
                                             float* __restrict__ out) {
    __shared__ float fl[160];
    __shared__ float h[512];
    int b = blockIdx.x, tid = threadIdx.x;
    if (tid < 160) fl[tid] = v[b * 160 + tid];
    __syncthreads();
    for (int j = tid; j < 512; j += 256) {
        float s = b1[j];
#pragma unroll 8
        for (int k = 0; k < 160; ++k) s += fl[k] * w1t[k * 512 + j];
        h[j] = fmaxf(s, 0.f);
    }
    __syncthreads();
    int wave = tid >> 6, lane = tid & 63;
    for (int j = wave; j < 9; j += 4) {
        float p = 0.f;
#pragma unroll
        for (int l = lane; l < 512; l += 64) p += h[l] * w2[j * 512 + l];
#pragma unroll
        for (int off = 32; off > 0; off >>= 1) p += __shfl_down(p, off, 64);
        if (lane == 0) out[b * 9 + j] = 1.f / (1.f + expf(-(p + b2[j])));
    }
}

// ---------------- launch ----------------
extern "C" void kernel_launch(void* const* d_in, const int* in_sizes, int n_in,
                              void* d_out, int out_size, void* d_ws, size_t ws_size,
                              hipStream_t stream) {
    const float* data   = (const float*)d_in[0];
    const float* conv_w = (const float*)d_in[1];
    const float* conv_b = (const float*)d_in[2];
    const float* pc_w   = (const float*)d_in[3];
    const float* pc_b   = (const float*)d_in[4];
    const float* W      = (const float*)d_in[5];
    const float* enc_w1 = (const float*)d_in[6];
    const float* enc_b1 = (const float*)d_in[7];
    const float* enc_w2 = (const float*)d_in[8];
    const float* enc_b2 = (const float*)d_in[9];

    char* ws = (char*)d_ws;
    uint8_t* xt8   = (uint8_t*)(ws + 0);           //  52,428,800
    uint8_t* w2t8  = (uint8_t*)(ws + 52428800);    //   5,308,416 -> 57,737,216
    bf16_t*  parts = (bf16_t*)(ws + 57737216);     //  18,874,368 (2 x 4,718,592 bf16) -> 76,611,584
    bf16_t*  Acol  = (bf16_t*)(ws + 76611584);     //  42,598,400 (dead after c1gemm) -> 119,209,984
    // overlays in Acol region (used only after squash):
    bf16_t*  uT    = (bf16_t*)(ws + 76611584);     //   9,437,184
    bf16_t*  cw2T  = (bf16_t*)(ws + 86048768);     //   2,949,120
    float*   sp    = (float*)(ws + 88997888);      //  11,796,480 -> 100,794,368
    bf16_t*  ub    = (bf16_t*)(ws + 119209984);    //   9,437,184 -> 128,647,168
    float*   v     = (float*)(ws + 128647168);     //     327,680
    bf16_t*  vT    = (bf16_t*)(ws + 128974848);    //     163,840
    float*   w1t   = (float*)(ws + 129138688);     //     327,680
    float*   bij   = (float*)(ws + 129466368);     //      46,080
    bf16_t*  Bc1   = (bf16_t*)(ws + 129512448);    //      53,248 -> 129,565,696 total
    float*   outp  = (float*)d_out;

    hipLaunchKernelGGL(k_init_bij, dim3(45), dim3(256), 0, stream, bij);
    hipLaunchKernelGGL(k_w1t, dim3(320), dim3(256), 0, stream, enc_w1, w1t);
    hipLaunchKernelGGL(k_w1c, dim3(104), dim3(256), 0, stream, conv_w, Bc1);
    hipLaunchKernelGGL(k_w2t, dim3(256), dim3(256), 0, stream, pc_w, w2t8);
    hipLaunchKernelGGL(k_im2col, dim3(512), dim3(256), 0, stream, data, Acol);
    hipLaunchKernelGGL(k_c1gemm, dim3(800), dim3(512), 0, stream, Acol, Bc1, conv_b, xt8);
    hipLaunchKernelGGL(k_pcgemm, dim3(576), dim3(256), 0, stream, xt8, w2t8, parts);
    hipLaunchKernelGGL(k_squash, dim3(512), dim3(256), 0, stream, parts, pc_b, ub);
    hipLaunchKernelGGL(k_uT, dim3(1152), dim3(256), 0, stream, ub, uT);
    for (int it = 0; it < 3; ++it) {
        hipLaunchKernelGGL(k_fold, dim3(5760), dim3(256), 0, stream, bij, W, cw2T);
        hipLaunchKernelGGL(k_rgemm, dim3(288), dim3(256), 0, stream, ub, cw2T, sp, 9216, 4, 8);
        hipLaunchKernelGGL(k_vcomp, dim3(320), dim3(256), 0, stream, sp, v, vT);
        if (it < 2) {
            hipLaunchKernelGGL(k_ggemm2, dim3(144), dim3(256), 0, stream, uT, vT, W, bij);
        }
    }
    hipLaunchKernelGGL(k_enc, dim3(512), dim3(256), 0, stream, v, w1t, enc_b1, enc_w2, enc_b2, outp);
}